// Round 1
// baseline (171.342 us; speedup 1.0000x reference)
//
#include <hip/hip_runtime.h>
#include <math.h>

// NoisyTopExpertsPerItemRouter: B=8,S=4096,D=1024,E=64,K=2
#define B_ 8
#define S_ 4096
#define D_ 1024
#define E_ 64
#define NOISE_STD 0.015625f     // max(1/64, 1e-6)
#define INV_NOISE_STD 64.0f
#define OUT_GATES (B_ * S_ * E_)   // 2097152

// workspace layout (float offsets)
#define WS_WG   0        // Wg[64][1024] = gamma[d]*W[e][d]
#define WS_GW   65536    // GW[64] = sum_d gamma*W
#define WS_BW   65600    // BW[64] = sum_d beta*W
#define WS_IMP  65664    // imp[8][64]  (clean-gate sums over s)
#define WS_SGN  66176    // sum gates_noisy per expert [64]
#define WS_CNT  66240    // top1 counts per expert [64]
#define WS_SP   66304    // sumP, sumP2
#define WS_NACC 642      // floats to zero starting at WS_IMP

__device__ __forceinline__ float wave_sum64(float v) {
#pragma unroll
  for (int o = 32; o > 0; o >>= 1) v += __shfl_xor(v, o);
  return v;
}
__device__ __forceinline__ float wave_max64(float v) {
#pragma unroll
  for (int o = 32; o > 0; o >>= 1) v = fmaxf(v, __shfl_xor(v, o));
  return v;
}
__device__ __forceinline__ float wave_secondmax64(float v) {
  float m1 = v, m2 = -INFINITY;
#pragma unroll
  for (int o = 32; o > 0; o >>= 1) {
    float o1 = __shfl_xor(m1, o);
    float o2 = __shfl_xor(m2, o);
    float hi = fmaxf(m1, o1);
    float lo = fminf(m1, o1);
    m1 = hi;
    m2 = fmaxf(lo, fmaxf(m2, o2));
  }
  return m2;
}
__device__ __forceinline__ int wave_argmax64(float v, int lane) {
  float bv = v; int bi = lane;
#pragma unroll
  for (int o = 32; o > 0; o >>= 1) {
    float ov = __shfl_xor(bv, o);
    int oi = __shfl_xor(bi, o);
    if (ov > bv || (ov == bv && oi < bi)) { bv = ov; bi = oi; }
  }
  return bi;
}

// ---------------- prep: Wg = gamma*W, GW/BW reductions, zero accumulators ----
__global__ void router_prep(const float* __restrict__ W,
                            const float* __restrict__ gamma,
                            const float* __restrict__ beta,
                            float* __restrict__ ws) {
  if (blockIdx.x == E_) {
    for (int i = threadIdx.x; i < WS_NACC; i += 256) ws[WS_IMP + i] = 0.0f;
    return;
  }
  const int e = blockIdx.x;
  float gw = 0.0f, bw = 0.0f;
  for (int d = threadIdx.x; d < D_; d += 256) {
    float wv = W[e * D_ + d];
    float gv = gamma[d];
    float pv = gv * wv;
    ws[WS_WG + e * D_ + d] = pv;
    gw += pv;
    bw += beta[d] * wv;
  }
  __shared__ float sred[8];
  gw = wave_sum64(gw);
  bw = wave_sum64(bw);
  const int w = threadIdx.x >> 6, lane = threadIdx.x & 63;
  if (lane == 0) { sred[w] = gw; sred[4 + w] = bw; }
  __syncthreads();
  if (threadIdx.x == 0) {
    ws[WS_GW + e] = sred[0] + sred[1] + sred[2] + sred[3];
    ws[WS_BW + e] = sred[4] + sred[5] + sred[6] + sred[7];
  }
}

// ---------------- main: fused LN-stats + GEMM + softmax/top2/erf epilogue ----
// block = 256 threads, owns rows {b=0..7} x {s0..s0+7} (64 rows)
// row index r: b = r&7, sl = r>>3  (wave w handles rows 16w..16w+15 -> sl {2w,2w+1}, all b)
__global__ void __launch_bounds__(256, 2)
router_main(const float* __restrict__ X, const float* __restrict__ noise,
            float* __restrict__ out, float* __restrict__ ws) {
  __shared__ float Xl[64 * 132];   // X chunk [64 rows][128+pad4]; later reused as logits Lg[64][65]
  __shared__ float Wl[64 * 132];   // Wg chunk [64 experts][128+pad4]; later reused as impacc[8][64]
  __shared__ float mu_s[64], rstd_s[64];
  __shared__ float gw_s[64], bw_s[64];
  __shared__ float red_s[8];

  const float* __restrict__ Wg = ws + WS_WG;
  const int t = threadIdx.x;
  const int s0 = blockIdx.x * 8;

  if (t < 64) { gw_s[t] = ws[WS_GW + t]; bw_s[t] = ws[WS_BW + t]; }

  // staging assignment: thread t stages row r_st (X) and expert r_st (W), quarter q
  const int r_st = t >> 2;
  const int q = t & 3;
  const int b_st = r_st & 7;
  const int sl_st = r_st >> 3;
  const size_t xbase = ((size_t)b_st * S_ + (size_t)(s0 + sl_st)) * D_;
  const size_t wbase = (size_t)r_st * D_;

  // gemm assignment: 4 rows x 4 experts per thread
  const int rg = t >> 4;   // rows 4*rg .. 4*rg+3
  const int eg = t & 15;   // experts eg + 16*j

  float sv = 0.0f, sv2 = 0.0f;
  float acc[4][4];
#pragma unroll
  for (int i = 0; i < 4; i++)
#pragma unroll
    for (int j = 0; j < 4; j++) acc[i][j] = 0.0f;

  for (int dc = 0; dc < 8; ++dc) {
    __syncthreads();
    // stage X chunk + W chunk; fold LN stats into the staging pass
#pragma unroll
    for (int k = 0; k < 8; ++k) {
      const int off = dc * 128 + k * 16 + q * 4;
      const int loff = k * 16 + q * 4;
      float4 xv = *(const float4*)(X + xbase + off);
      float4 wv = *(const float4*)(Wg + wbase + off);
      *(float4*)(Xl + r_st * 132 + loff) = xv;
      *(float4*)(Wl + r_st * 132 + loff) = wv;
      sv  += xv.x + xv.y + xv.z + xv.w;
      sv2 += xv.x * xv.x + xv.y * xv.y + xv.z * xv.z + xv.w * xv.w;
    }
    __syncthreads();
    // GEMM on chunk: acc[i][j] += X[4rg+i][:] . Wg[eg+16j][:]
#pragma unroll 4
    for (int dd = 0; dd < 128; dd += 4) {
      float4 a[4], wv[4];
#pragma unroll
      for (int i = 0; i < 4; i++) a[i] = *(const float4*)(Xl + (4 * rg + i) * 132 + dd);
#pragma unroll
      for (int j = 0; j < 4; j++) wv[j] = *(const float4*)(Wl + (eg + 16 * j) * 132 + dd);
#pragma unroll
      for (int i = 0; i < 4; i++)
#pragma unroll
        for (int j = 0; j < 4; j++)
          acc[i][j] += a[i].x * wv[j].x + a[i].y * wv[j].y +
                       a[i].z * wv[j].z + a[i].w * wv[j].w;
    }
  }
  __syncthreads();  // all GEMM LDS reads done; Xl/Wl reusable

  // finalize per-row LN stats (reduce over the 4 staging threads of each row)
  sv  += __shfl_xor(sv, 1);  sv  += __shfl_xor(sv, 2);
  sv2 += __shfl_xor(sv2, 1); sv2 += __shfl_xor(sv2, 2);
  if (q == 0) {
    float mu = sv * (1.0f / (float)D_);
    float var = sv2 * (1.0f / (float)D_) - mu * mu;
    mu_s[r_st] = mu;
    rstd_s[r_st] = rsqrtf(var + 1e-5f);
  }
  float* impacc = Wl;  // [8][64]
  for (int idx = t; idx < 8 * 64; idx += 256) impacc[idx] = 0.0f;
  __syncthreads();

  // logits into LDS (unshifted; the reference's max-shift cancels everywhere)
  float* Lg = Xl;  // [64][65]
#pragma unroll
  for (int i = 0; i < 4; i++) {
    const int r = 4 * rg + i;
    const float mu = mu_s[r], rs = rstd_s[r];
#pragma unroll
    for (int j = 0; j < 4; j++) {
      const int e = eg + 16 * j;
      Lg[r * 65 + e] = rs * (acc[i][j] - mu * gw_s[e]) + bw_s[e];
    }
  }
  __syncthreads();

  // epilogue: one wave per row, lane = expert
  const int w = t >> 6, lane = t & 63;
  float pm0 = 0.0f, pm1 = 0.0f, gnsum = 0.0f, cntf = 0.0f;
  for (int rr = 0; rr < 16; ++rr) {
    const int r = 16 * w + rr;
    const int b = r & 7, sl = r >> 3;
    const int s = s0 + sl;
    const float l = Lg[r * 65 + lane];

    // clean softmax -> importance accumulation
    float m = wave_max64(l);
    float ge = expf(l - m);
    float gsum = wave_sum64(ge);
    float gate = ge / gsum;
    atomicAdd(&impacc[b * 64 + lane], gate);

    // noisy logits
    const float nz = noise[((size_t)b * S_ + s) * E_ + lane];
    const float ln = l + NOISE_STD * nz;

    // noisy softmax -> output + mean_gates accumulation
    float mn = wave_max64(ln);
    float gen = expf(ln - mn);
    float gdsum = wave_sum64(gen);
    float gn = gen / gdsum;
    out[((size_t)b * S_ + s) * E_ + lane] = gn;
    gnsum += gn;

    // top-1 of noisy (== argmax of gates_noisy), first-index tiebreak
    int am = wave_argmax64(ln, lane);
    if (am == lane) cntf += 1.0f;

    // threshold = 2nd largest noisy logit; p = Phi(clip((thr-l)/sigma))
    float thr = wave_secondmax64(ln);
    float z = fminf(fmaxf((thr - l) * INV_NOISE_STD, -10.0f), 10.0f);
    float p = 0.5f * (1.0f + erff(z * 0.70710678118654752f));
    if (rr < 8) pm0 += p; else pm1 += p;   // rr<8 -> sl=2w, else sl=2w+1 (sums over all 8 b)
  }

  // per-expert global accumulators
  atomicAdd(&ws[WS_SGN + lane], gnsum);
  atomicAdd(&ws[WS_CNT + lane], cntf);

  // p_mean stats: pm/8 per (sl,e); accumulate sum and sum of squares
  float c1 = (pm0 + pm1) * 0.125f;
  float c2 = (pm0 * pm0 + pm1 * pm1) * (1.0f / 64.0f);
  c1 = wave_sum64(c1);
  c2 = wave_sum64(c2);
  if (lane == 0) { red_s[w * 2] = c1; red_s[w * 2 + 1] = c2; }
  __syncthreads();

  for (int idx = t; idx < 8 * 64; idx += 256) atomicAdd(&ws[WS_IMP + idx], impacc[idx]);
  if (t == 0) {
    atomicAdd(&ws[WS_SP + 0], red_s[0] + red_s[2] + red_s[4] + red_s[6]);
    atomicAdd(&ws[WS_SP + 1], red_s[1] + red_s[3] + red_s[5] + red_s[7]);
  }
}

// ---------------- finalize: 3 scalar losses ----------------
__global__ void router_final(const float* __restrict__ ws, float* __restrict__ out) {
  const int lane = threadIdx.x;  // 64 threads = 1 wave
  // importance loss: mean_b (std_ddof1 / mean)^2 over imp[b][:]
  float impsum = 0.0f;
  for (int b = 0; b < B_; ++b) {
    float v = ws[WS_IMP + b * 64 + lane];
    float s = wave_sum64(v);
    float mean = s * (1.0f / 64.0f);
    float d = v - mean;
    float ss = wave_sum64(d * d);
    impsum += (ss / 63.0f) / (mean * mean);
  }
  float importance = impsum * (1.0f / (float)B_);
  // load loss: CV^2 (ddof=0) over p_mean (S*E elements)
  const float N = (float)(S_ * E_);
  float meanp = ws[WS_SP + 0] / N;
  float varp = ws[WS_SP + 1] / N - meanp * meanp;
  float load = varp / (meanp * meanp);
  // gshard loss: mean_e(mean_top1 * mean_gates) * E^2
  const float inv_rows = 1.0f / (float)(B_ * S_);
  float te = (ws[WS_CNT + lane] * inv_rows) * (ws[WS_SGN + lane] * inv_rows);
  float gs = wave_sum64(te) * (float)E_;  // (sum/E)*E^2 = sum*E
  if (lane == 0) {
    out[OUT_GATES + 0] = importance + load;  // aux (GSHARD_W = 0)
    out[OUT_GATES + 1] = gs;
    out[OUT_GATES + 2] = importance;
    out[OUT_GATES + 3] = load;
  }
}

extern "C" void kernel_launch(void* const* d_in, const int* in_sizes, int n_in,
                              void* d_out, int out_size, void* d_ws, size_t ws_size,
                              hipStream_t stream) {
  (void)in_sizes; (void)n_in; (void)out_size; (void)ws_size;
  const float* X     = (const float*)d_in[0];
  const float* noise = (const float*)d_in[1];
  const float* gamma = (const float*)d_in[2];
  const float* beta  = (const float*)d_in[3];
  const float* W     = (const float*)d_in[4];
  float* out = (float*)d_out;
  float* ws  = (float*)d_ws;

  router_prep<<<dim3(E_ + 1), dim3(256), 0, stream>>>(W, gamma, beta, ws);
  router_main<<<dim3(S_ / 8), dim3(256), 0, stream>>>(X, noise, out, ws);
  router_final<<<dim3(1), dim3(64), 0, stream>>>(ws, out);
}

// Round 2
// 147.980 us; speedup vs baseline: 1.1579x; 1.1579x over previous
//
#include <hip/hip_runtime.h>
#include <hip/hip_bf16.h>
#include <math.h>

// NoisyTopExpertsPerItemRouter: B=8,S=4096,D=1024,E=64,K=2
#define B_ 8
#define S_ 4096
#define D_ 1024
#define E_ 64
#define NOISE_STD 0.015625f     // max(1/64, 1e-6)
#define INV_NOISE_STD 64.0f
#define OUT_GATES (B_ * S_ * E_)   // 2097152

typedef __attribute__((ext_vector_type(8))) short short8;
typedef __attribute__((ext_vector_type(4))) float f32x4;

// workspace layout (float offsets)
// [0 .. 32768): Wg as bf16 [64][1024] (ushort), i.e. 32768 floats of space
#define WS_GW   32768    // GW[64] = sum_d bf16(gamma*W)
#define WS_BW   32832    // BW[64] = sum_d beta*W
#define WS_IMP  32896    // imp[8][64]
#define WS_SGN  33408    // sum gates_noisy per expert [64]
#define WS_CNT  33472    // top1 counts per expert [64]
#define WS_SP   33536    // sumP, sumP2
#define WS_NACC 642      // floats to zero starting at WS_IMP

__device__ __forceinline__ float wave_sum64(float v) {
#pragma unroll
  for (int o = 32; o > 0; o >>= 1) v += __shfl_xor(v, o);
  return v;
}
__device__ __forceinline__ float wave_max64(float v) {
#pragma unroll
  for (int o = 32; o > 0; o >>= 1) v = fmaxf(v, __shfl_xor(v, o));
  return v;
}
__device__ __forceinline__ float wave_secondmax64(float v) {
  float m1 = v, m2 = -INFINITY;
#pragma unroll
  for (int o = 32; o > 0; o >>= 1) {
    float o1 = __shfl_xor(m1, o);
    float o2 = __shfl_xor(m2, o);
    float hi = fmaxf(m1, o1);
    float lo = fminf(m1, o1);
    m1 = hi;
    m2 = fmaxf(lo, fmaxf(m2, o2));
  }
  return m2;
}
__device__ __forceinline__ int wave_argmax64(float v, int lane) {
  float bv = v; int bi = lane;
#pragma unroll
  for (int o = 32; o > 0; o >>= 1) {
    float ov = __shfl_xor(bv, o);
    int oi = __shfl_xor(bi, o);
    if (ov > bv || (ov == bv && oi < bi)) { bv = ov; bi = oi; }
  }
  return bi;
}

// ---------------- prep: Wg(bf16) = gamma*W, GW/BW reductions, zero accums ----
__global__ void router_prep(const float* __restrict__ W,
                            const float* __restrict__ gamma,
                            const float* __restrict__ beta,
                            float* __restrict__ ws) {
  if (blockIdx.x == E_) {
    for (int i = threadIdx.x; i < WS_NACC; i += 256) ws[WS_IMP + i] = 0.0f;
    return;
  }
  const int e = blockIdx.x;
  unsigned short* wgb = (unsigned short*)ws;
  float gw = 0.0f, bw = 0.0f;
  for (int d = threadIdx.x; d < D_; d += 256) {
    float wv = W[e * D_ + d];
    float pv = gamma[d] * wv;
    union { __hip_bfloat16 h; unsigned short u; } cv;
    cv.h = __float2bfloat16(pv);
    wgb[e * D_ + d] = cv.u;
    gw += __bfloat162float(cv.h);   // sum of the ROUNDED values (consistency)
    bw += beta[d] * wv;
  }
  __shared__ float sred[8];
  gw = wave_sum64(gw);
  bw = wave_sum64(bw);
  const int w = threadIdx.x >> 6, lane = threadIdx.x & 63;
  if (lane == 0) { sred[w] = gw; sred[4 + w] = bw; }
  __syncthreads();
  if (threadIdx.x == 0) {
    ws[WS_GW + e] = sred[0] + sred[1] + sred[2] + sred[3];
    ws[WS_BW + e] = sred[4] + sred[5] + sred[6] + sred[7];
  }
}

// ---------------- main: direct-global bf16 MFMA + fused LN + epilogue -------
// block = 256 thr = 4 waves; block owns 64 rows: r in [0,64), b=r&7, sl=r>>3,
// s = blockIdx*8 + sl. Wave w computes rows 16w..16w+15 x all 64 experts.
__global__ void __launch_bounds__(256, 2)
router_main(const float* __restrict__ X, const float* __restrict__ noise,
            float* __restrict__ out, float* __restrict__ ws) {
  __shared__ float Lg[64 * 65];      // logits [row][expert], pad 65
  __shared__ float impacc[8 * 64];   // clean-gate sums per (b,e)
  __shared__ float red_s[8];

  const int t = threadIdx.x;
  const int w = t >> 6, lane = t & 63;
  const int s0 = blockIdx.x * 8;

  // MFMA geometry: lane&15 = local row (A) / expert-in-tile (B); lane>>4 = k-slice
  const int lrow = lane & 15;
  const int kh = lane >> 4;

  const int r_mf = 16 * w + lrow;            // block-local row this lane loads
  const int b_mf = r_mf & 7, sl_mf = r_mf >> 3;
  const float* __restrict__ xp =
      X + ((size_t)b_mf * S_ + (size_t)(s0 + sl_mf)) * D_ + kh * 8;

  const unsigned short* __restrict__ wgb = (const unsigned short*)ws;
  const unsigned short* __restrict__ bp0 = wgb + (0  + lrow) * D_ + kh * 8;
  const unsigned short* __restrict__ bp1 = wgb + (16 + lrow) * D_ + kh * 8;
  const unsigned short* __restrict__ bp2 = wgb + (32 + lrow) * D_ + kh * 8;
  const unsigned short* __restrict__ bp3 = wgb + (48 + lrow) * D_ + kh * 8;

  float sv = 0.0f, sv2 = 0.0f;
  f32x4 acc0 = {0.f, 0.f, 0.f, 0.f};
  f32x4 acc1 = {0.f, 0.f, 0.f, 0.f};
  f32x4 acc2 = {0.f, 0.f, 0.f, 0.f};
  f32x4 acc3 = {0.f, 0.f, 0.f, 0.f};

#pragma unroll 4
  for (int k0 = 0; k0 < D_; k0 += 32) {
    float4 a0 = *(const float4*)(xp + k0);
    float4 a1 = *(const float4*)(xp + k0 + 4);
    short8 b0 = *(const short8*)(bp0 + k0);
    short8 b1 = *(const short8*)(bp1 + k0);
    short8 b2 = *(const short8*)(bp2 + k0);
    short8 b3 = *(const short8*)(bp3 + k0);

    sv += (a0.x + a0.y) + (a0.z + a0.w) + (a1.x + a1.y) + (a1.z + a1.w);
    sv2 = fmaf(a0.x, a0.x, sv2); sv2 = fmaf(a0.y, a0.y, sv2);
    sv2 = fmaf(a0.z, a0.z, sv2); sv2 = fmaf(a0.w, a0.w, sv2);
    sv2 = fmaf(a1.x, a1.x, sv2); sv2 = fmaf(a1.y, a1.y, sv2);
    sv2 = fmaf(a1.z, a1.z, sv2); sv2 = fmaf(a1.w, a1.w, sv2);

    union { short8 s; __hip_bfloat162 h[4]; } u;
    u.h[0] = __float22bfloat162_rn(make_float2(a0.x, a0.y));
    u.h[1] = __float22bfloat162_rn(make_float2(a0.z, a0.w));
    u.h[2] = __float22bfloat162_rn(make_float2(a1.x, a1.y));
    u.h[3] = __float22bfloat162_rn(make_float2(a1.z, a1.w));

    acc0 = __builtin_amdgcn_mfma_f32_16x16x32_bf16(u.s, b0, acc0, 0, 0, 0);
    acc1 = __builtin_amdgcn_mfma_f32_16x16x32_bf16(u.s, b1, acc1, 0, 0, 0);
    acc2 = __builtin_amdgcn_mfma_f32_16x16x32_bf16(u.s, b2, acc2, 0, 0, 0);
    acc3 = __builtin_amdgcn_mfma_f32_16x16x32_bf16(u.s, b3, acc3, 0, 0, 0);
  }

  // LN stats: combine the 4 k-slice lanes of each row (lanes r, r+16, r+32, r+48)
  sv  += __shfl_xor(sv, 16);  sv  += __shfl_xor(sv, 32);
  sv2 += __shfl_xor(sv2, 16); sv2 += __shfl_xor(sv2, 32);
  float mu = sv * (1.0f / (float)D_);
  float var = sv2 * (1.0f / (float)D_) - mu * mu;
  float rs = rsqrtf(var + 1e-5f);

  const float gw0 = ws[WS_GW + 0  + lrow], bw0 = ws[WS_BW + 0  + lrow];
  const float gw1 = ws[WS_GW + 16 + lrow], bw1 = ws[WS_BW + 16 + lrow];
  const float gw2 = ws[WS_GW + 32 + lrow], bw2 = ws[WS_BW + 32 + lrow];
  const float gw3 = ws[WS_GW + 48 + lrow], bw3 = ws[WS_BW + 48 + lrow];

  // C/D layout: col(expert-in-tile)=lane&15, row=(lane>>4)*4+i  [m89-verified]
#pragma unroll
  for (int i = 0; i < 4; i++) {
    const int rloc = 16 * w + kh * 4 + i;
    const float mui = __shfl(mu, kh * 4 + i);   // lane (kh*4+i) holds row kh*4+i
    const float rsi = __shfl(rs, kh * 4 + i);
    Lg[rloc * 65 + 0  + lrow] = rsi * (acc0[i] - mui * gw0) + bw0;
    Lg[rloc * 65 + 16 + lrow] = rsi * (acc1[i] - mui * gw1) + bw1;
    Lg[rloc * 65 + 32 + lrow] = rsi * (acc2[i] - mui * gw2) + bw2;
    Lg[rloc * 65 + 48 + lrow] = rsi * (acc3[i] - mui * gw3) + bw3;
  }
  for (int idx = t; idx < 8 * 64; idx += 256) impacc[idx] = 0.0f;
  __syncthreads();

  // epilogue: one wave per row, lane = expert
  float pm0 = 0.0f, pm1 = 0.0f, gnsum = 0.0f, cntf = 0.0f;
  for (int rr = 0; rr < 16; ++rr) {
    const int r = 16 * w + rr;
    const int b = r & 7, sl = r >> 3;
    const int s = s0 + sl;
    const float l = Lg[r * 65 + lane];

    // clean softmax -> importance accumulation
    float m = wave_max64(l);
    float ge = expf(l - m);
    float gsum = wave_sum64(ge);
    float gate = ge / gsum;
    atomicAdd(&impacc[b * 64 + lane], gate);

    // noisy logits
    const float nz = noise[((size_t)b * S_ + s) * E_ + lane];
    const float ln = l + NOISE_STD * nz;

    // noisy softmax -> output + mean_gates accumulation
    float mn = wave_max64(ln);
    float gen = expf(ln - mn);
    float gdsum = wave_sum64(gen);
    float gn = gen / gdsum;
    out[((size_t)b * S_ + s) * E_ + lane] = gn;
    gnsum += gn;

    // top-1 of noisy, first-index tiebreak
    int am = wave_argmax64(ln, lane);
    if (am == lane) cntf += 1.0f;

    // threshold = 2nd largest noisy logit; p = Phi(clip((thr-l)/sigma))
    float thr = wave_secondmax64(ln);
    float z = fminf(fmaxf((thr - l) * INV_NOISE_STD, -10.0f), 10.0f);
    float p = 0.5f * (1.0f + erff(z * 0.70710678118654752f));
    if (rr < 8) pm0 += p; else pm1 += p;   // rr<8 -> sl=2w, else sl=2w+1
  }

  atomicAdd(&ws[WS_SGN + lane], gnsum);
  atomicAdd(&ws[WS_CNT + lane], cntf);

  float c1 = (pm0 + pm1) * 0.125f;
  float c2 = (pm0 * pm0 + pm1 * pm1) * (1.0f / 64.0f);
  c1 = wave_sum64(c1);
  c2 = wave_sum64(c2);
  if (lane == 0) { red_s[w * 2] = c1; red_s[w * 2 + 1] = c2; }
  __syncthreads();

  for (int idx = t; idx < 8 * 64; idx += 256) atomicAdd(&ws[WS_IMP + idx], impacc[idx]);
  if (t == 0) {
    atomicAdd(&ws[WS_SP + 0], red_s[0] + red_s[2] + red_s[4] + red_s[6]);
    atomicAdd(&ws[WS_SP + 1], red_s[1] + red_s[3] + red_s[5] + red_s[7]);
  }
}

// ---------------- finalize: 3 scalar losses ----------------
__global__ void router_final(const float* __restrict__ ws, float* __restrict__ out) {
  const int lane = threadIdx.x;  // 64 threads = 1 wave
  float impsum = 0.0f;
  for (int b = 0; b < B_; ++b) {
    float v = ws[WS_IMP + b * 64 + lane];
    float s = wave_sum64(v);
    float mean = s * (1.0f / 64.0f);
    float d = v - mean;
    float ss = wave_sum64(d * d);
    impsum += (ss / 63.0f) / (mean * mean);
  }
  float importance = impsum * (1.0f / (float)B_);
  const float N = (float)(S_ * E_);
  float meanp = ws[WS_SP + 0] / N;
  float varp = ws[WS_SP + 1] / N - meanp * meanp;
  float load = varp / (meanp * meanp);
  const float inv_rows = 1.0f / (float)(B_ * S_);
  float te = (ws[WS_CNT + lane] * inv_rows) * (ws[WS_SGN + lane] * inv_rows);
  float gs = wave_sum64(te) * (float)E_;
  if (lane == 0) {
    out[OUT_GATES + 0] = importance + load;  // aux (GSHARD_W = 0)
    out[OUT_GATES + 1] = gs;
    out[OUT_GATES + 2] = importance;
    out[OUT_GATES + 3] = load;
  }
}

extern "C" void kernel_launch(void* const* d_in, const int* in_sizes, int n_in,
                              void* d_out, int out_size, void* d_ws, size_t ws_size,
                              hipStream_t stream) {
  (void)in_sizes; (void)n_in; (void)out_size; (void)ws_size;
  const float* X     = (const float*)d_in[0];
  const float* noise = (const float*)d_in[1];
  const float* gamma = (const float*)d_in[2];
  const float* beta  = (const float*)d_in[3];
  const float* W     = (const float*)d_in[4];
  float* out = (float*)d_out;
  float* ws  = (float*)d_ws;

  router_prep<<<dim3(E_ + 1), dim3(256), 0, stream>>>(W, gamma, beta, ws);
  router_main<<<dim3(S_ / 8), dim3(256), 0, stream>>>(X, noise, out, ws);
  router_final<<<dim3(1), dim3(64), 0, stream>>>(ws, out);
}

// Round 3
// 85.178 us; speedup vs baseline: 2.0116x; 1.7373x over previous
//
#include <hip/hip_runtime.h>
#include <hip/hip_bf16.h>
#include <math.h>

// NoisyTopExpertsPerItemRouter: B=8,S=4096,D=1024,E=64,K=2
#define B_ 8
#define S_ 4096
#define D_ 1024
#define E_ 64
#define NOISE_STD 0.015625f     // max(1/64, 1e-6)
#define INV_NOISE_STD 64.0f
#define OUT_GATES (B_ * S_ * E_)   // 2097152
#define APART 32                   // striped global accumulator copies

typedef __attribute__((ext_vector_type(8))) short short8;
typedef __attribute__((ext_vector_type(4))) float f32x4;

// workspace layout (float offsets)
// [0 .. 32768): Wg as bf16 [64][1024] (ushort)
#define WS_GW   32768                    // GW[64]
#define WS_BW   32832                    // BW[64]
#define WS_IMP  32896                    // APART x [8][64]
#define WS_SGN  (WS_IMP + APART * 512)   // APART x [64]
#define WS_CNT  (WS_SGN + APART * 64)    // APART x [64]
#define WS_SP   (WS_CNT + APART * 64)    // APART x [2]
#define WS_NACC (APART * 512 + APART * 64 + APART * 64 + APART * 2)

__device__ __forceinline__ float wave_sum64(float v) {
#pragma unroll
  for (int o = 32; o > 0; o >>= 1) v += __shfl_xor(v, o);
  return v;
}
__device__ __forceinline__ float wave_max64(float v) {
#pragma unroll
  for (int o = 32; o > 0; o >>= 1) v = fmaxf(v, __shfl_xor(v, o));
  return v;
}
__device__ __forceinline__ float wave_secondmax64(float v) {
  float m1 = v, m2 = -INFINITY;
#pragma unroll
  for (int o = 32; o > 0; o >>= 1) {
    float o1 = __shfl_xor(m1, o);
    float o2 = __shfl_xor(m2, o);
    float hi = fmaxf(m1, o1);
    float lo = fminf(m1, o1);
    m1 = hi;
    m2 = fmaxf(lo, fmaxf(m2, o2));
  }
  return m2;
}
__device__ __forceinline__ int wave_argmax64(float v, int lane) {
  float bv = v; int bi = lane;
#pragma unroll
  for (int o = 32; o > 0; o >>= 1) {
    float ov = __shfl_xor(bv, o);
    int oi = __shfl_xor(bi, o);
    if (ov > bv || (ov == bv && oi < bi)) { bv = ov; bi = oi; }
  }
  return bi;
}

// ---------------- prep: Wg(bf16) = gamma*W, GW/BW reductions, zero accums ----
__global__ void router_prep(const float* __restrict__ W,
                            const float* __restrict__ gamma,
                            const float* __restrict__ beta,
                            float* __restrict__ ws) {
  if (blockIdx.x >= E_) {
    const int z = blockIdx.x - E_;   // 0..7
    for (int i = z * 256 + threadIdx.x; i < WS_NACC; i += 8 * 256)
      ws[WS_IMP + i] = 0.0f;
    return;
  }
  const int e = blockIdx.x;
  unsigned short* wgb = (unsigned short*)ws;
  float gw = 0.0f, bw = 0.0f;
  for (int d = threadIdx.x; d < D_; d += 256) {
    float wv = W[e * D_ + d];
    float pv = gamma[d] * wv;
    union { __hip_bfloat16 h; unsigned short u; } cv;
    cv.h = __float2bfloat16(pv);
    wgb[e * D_ + d] = cv.u;
    gw += __bfloat162float(cv.h);   // sum of ROUNDED values (consistency)
    bw += beta[d] * wv;
  }
  __shared__ float sred[8];
  gw = wave_sum64(gw);
  bw = wave_sum64(bw);
  const int w = threadIdx.x >> 6, lane = threadIdx.x & 63;
  if (lane == 0) { sred[w] = gw; sred[4 + w] = bw; }
  __syncthreads();
  if (threadIdx.x == 0) {
    ws[WS_GW + e] = sred[0] + sred[1] + sred[2] + sred[3];
    ws[WS_BW + e] = sred[4] + sred[5] + sred[6] + sred[7];
  }
}

// ---------------- main: K-split-4 bf16 MFMA + fused LN + epilogue -----------
// block = 256 thr = 4 waves; block owns 16 rows: r in [0,16), b=r&7, sl=r>>3,
// s = 2*blockIdx + sl. Wave w is K-slice [256w, 256w+256) for ALL 16 rows.
// Combine partial accs via LDS, then wave w computes experts [16w,16w+16).
__global__ void __launch_bounds__(256, 8)
router_main(const float* __restrict__ X, const float* __restrict__ noise,
            float* __restrict__ out, float* __restrict__ ws) {
  __shared__ f32x4 smbuf4[1024];           // 16KB: acc parts, then epilogue arrays
  __shared__ float svp[4][16], sv2p[4][16];
  float* smbuf = (float*)smbuf4;

  const int t = threadIdx.x;
  const int w = t >> 6, lane = t & 63;
  const int lrow = lane & 15, kh = lane >> 4;
  const int bid = blockIdx.x;
  const int s0 = bid * 2;

  // A-row this lane loads: block-local row = lrow
  const int b_mf = lrow & 7, sl_mf = lrow >> 3;
  const int wko = w * 256 + kh * 8;        // this wave's K-chunk + lane k-slice
  const float* __restrict__ xp =
      X + ((size_t)b_mf * S_ + (size_t)(s0 + sl_mf)) * D_ + wko;
  const unsigned short* __restrict__ wgb = (const unsigned short*)ws;
  const unsigned short* __restrict__ bp0 = wgb + (0  + lrow) * D_ + wko;
  const unsigned short* __restrict__ bp1 = wgb + (16 + lrow) * D_ + wko;
  const unsigned short* __restrict__ bp2 = wgb + (32 + lrow) * D_ + wko;
  const unsigned short* __restrict__ bp3 = wgb + (48 + lrow) * D_ + wko;

  float sv = 0.0f, sv2 = 0.0f;
  f32x4 acc0 = {0.f, 0.f, 0.f, 0.f};
  f32x4 acc1 = {0.f, 0.f, 0.f, 0.f};
  f32x4 acc2 = {0.f, 0.f, 0.f, 0.f};
  f32x4 acc3 = {0.f, 0.f, 0.f, 0.f};

#pragma unroll 4
  for (int k0 = 0; k0 < 256; k0 += 32) {
    float4 a0 = *(const float4*)(xp + k0);
    float4 a1 = *(const float4*)(xp + k0 + 4);
    short8 b0 = *(const short8*)(bp0 + k0);
    short8 b1 = *(const short8*)(bp1 + k0);
    short8 b2 = *(const short8*)(bp2 + k0);
    short8 b3 = *(const short8*)(bp3 + k0);

    sv += (a0.x + a0.y) + (a0.z + a0.w) + (a1.x + a1.y) + (a1.z + a1.w);
    sv2 = fmaf(a0.x, a0.x, sv2); sv2 = fmaf(a0.y, a0.y, sv2);
    sv2 = fmaf(a0.z, a0.z, sv2); sv2 = fmaf(a0.w, a0.w, sv2);
    sv2 = fmaf(a1.x, a1.x, sv2); sv2 = fmaf(a1.y, a1.y, sv2);
    sv2 = fmaf(a1.z, a1.z, sv2); sv2 = fmaf(a1.w, a1.w, sv2);

    union { short8 s; __hip_bfloat162 h[4]; } u;
    u.h[0] = __float22bfloat162_rn(make_float2(a0.x, a0.y));
    u.h[1] = __float22bfloat162_rn(make_float2(a0.z, a0.w));
    u.h[2] = __float22bfloat162_rn(make_float2(a1.x, a1.y));
    u.h[3] = __float22bfloat162_rn(make_float2(a1.z, a1.w));

    acc0 = __builtin_amdgcn_mfma_f32_16x16x32_bf16(u.s, b0, acc0, 0, 0, 0);
    acc1 = __builtin_amdgcn_mfma_f32_16x16x32_bf16(u.s, b1, acc1, 0, 0, 0);
    acc2 = __builtin_amdgcn_mfma_f32_16x16x32_bf16(u.s, b2, acc2, 0, 0, 0);
    acc3 = __builtin_amdgcn_mfma_f32_16x16x32_bf16(u.s, b3, acc3, 0, 0, 0);
  }

  // per-row LN stats partial (this wave's 256 k's): combine 4 kh lanes
  sv  += __shfl_xor(sv, 16);  sv  += __shfl_xor(sv, 32);
  sv2 += __shfl_xor(sv2, 16); sv2 += __shfl_xor(sv2, 32);
  if (lane < 16) { svp[w][lane] = sv; sv2p[w][lane] = sv2; }

  // publish acc partials: part[(chain*4 + ks)*64 + lane] (16B lane stride)
  {
    f32x4* P = smbuf4;
    P[(0 * 4 + w) * 64 + lane] = acc0;
    P[(1 * 4 + w) * 64 + lane] = acc1;
    P[(2 * 4 + w) * 64 + lane] = acc2;
    P[(3 * 4 + w) * 64 + lane] = acc3;
  }
  __syncthreads();

  // wave w takes over expert tile w: sum chain w across the 4 K-slices
  f32x4 asum;
  {
    const f32x4* P = smbuf4;
    f32x4 p0 = P[(w * 4 + 0) * 64 + lane];
    f32x4 p1 = P[(w * 4 + 1) * 64 + lane];
    f32x4 p2 = P[(w * 4 + 2) * 64 + lane];
    f32x4 p3 = P[(w * 4 + 3) * 64 + lane];
    asum = (p0 + p1) + (p2 + p3);
  }
  const float svr  = (svp[0][lrow] + svp[1][lrow]) + (svp[2][lrow] + svp[3][lrow]);
  const float sv2r = (sv2p[0][lrow] + sv2p[1][lrow]) + (sv2p[2][lrow] + sv2p[3][lrow]);
  float mu = svr * (1.0f / (float)D_);
  float var = sv2r * (1.0f / (float)D_) - mu * mu;
  float rs = rsqrtf(var + 1e-5f);
  const float gwv = ws[WS_GW + 16 * w + lrow];
  const float bwv = ws[WS_BW + 16 * w + lrow];
  __syncthreads();   // all partial reads done; smbuf reusable

  float* Lg     = smbuf;          // [16][65] = 1040
  float* impacc = smbuf + 1040;   // [8][64]  = 512
  float* pmacc  = smbuf + 1552;   // [2][64]  = 128
  float* sgnacc = smbuf + 1680;   // [64]
  float* cntacc = smbuf + 1744;   // [64] -> end 1808 < 4096

  // C/D layout: col(expert-in-tile)=lane&15, row=(lane>>4)*4+i  [m89-verified]
#pragma unroll
  for (int i = 0; i < 4; i++) {
    const int rloc = kh * 4 + i;
    const float mui = __shfl(mu, kh * 4 + i);   // lane (kh*4+i) holds row kh*4+i
    const float rsi = __shfl(rs, kh * 4 + i);
    Lg[rloc * 65 + 16 * w + lrow] = rsi * (asum[i] - mui * gwv) + bwv;
  }
  for (int idx = t; idx < 768; idx += 256) impacc[idx] = 0.0f;  // imp+pm+sgn+cnt
  __syncthreads();

  // epilogue: wave w owns rows 4w..4w+3 (all same sl = w>>1), lane = expert
  const int slw = w >> 1;
  const int s = s0 + slw;
  float nzv[4];
#pragma unroll
  for (int rr = 0; rr < 4; rr++) {
    const int b = (4 * w + rr) & 7;
    nzv[rr] = noise[((size_t)b * S_ + s) * E_ + lane];
  }
  float pm = 0.0f, gnsum = 0.0f, cntf = 0.0f;
#pragma unroll
  for (int rr = 0; rr < 4; rr++) {
    const int r = 4 * w + rr;
    const int b = r & 7;
    const float l = Lg[r * 65 + lane];

    // clean softmax -> importance accumulation
    float m = wave_max64(l);
    float ge = expf(l - m);
    float gsum = wave_sum64(ge);
    atomicAdd(&impacc[b * 64 + lane], ge / gsum);

    // noisy logits
    const float ln = l + NOISE_STD * nzv[rr];
    float mn = wave_max64(ln);
    float gen = expf(ln - mn);
    float gd = wave_sum64(gen);
    float gn = gen / gd;
    out[((size_t)b * S_ + s) * E_ + lane] = gn;
    gnsum += gn;

    // top-1 of noisy, first-index tiebreak
    int am = wave_argmax64(ln, lane);
    if (am == lane) cntf += 1.0f;

    // threshold = 2nd largest noisy logit; p = Phi(clip((thr-l)/sigma))
    float thr = wave_secondmax64(ln);
    float z = fminf(fmaxf((thr - l) * INV_NOISE_STD, -10.0f), 10.0f);
    pm += 0.5f * (1.0f + erff(z * 0.70710678118654752f));
  }
  atomicAdd(&pmacc[slw * 64 + lane], pm);
  atomicAdd(&sgnacc[lane], gnsum);
  atomicAdd(&cntacc[lane], cntf);
  __syncthreads();

  const int pc = bid & (APART - 1);
  if (w == 0) {
    // per-(s,e): P = sum_b p; c1 += P/8; c2 += (P/8)^2
    float P0 = pmacc[lane], P1 = pmacc[64 + lane];
    float c1 = (P0 + P1) * 0.125f;
    float c2 = (P0 * P0 + P1 * P1) * (1.0f / 64.0f);
    c1 = wave_sum64(c1);
    c2 = wave_sum64(c2);
    if (lane == 0) {
      atomicAdd(&ws[WS_SP + pc * 2 + 0], c1);
      atomicAdd(&ws[WS_SP + pc * 2 + 1], c2);
    }
  } else if (w == 1) {
    atomicAdd(&ws[WS_SGN + pc * 64 + lane], sgnacc[lane]);
  } else if (w == 2) {
    atomicAdd(&ws[WS_CNT + pc * 64 + lane], cntacc[lane]);
  }
  for (int idx = t; idx < 512; idx += 256)
    atomicAdd(&ws[WS_IMP + pc * 512 + idx], impacc[idx]);
}

// ---------------- finalize: reduce APART copies, 3 scalar losses ------------
__global__ void router_final(const float* __restrict__ ws, float* __restrict__ out) {
  const int lane = threadIdx.x;  // 64 threads = 1 wave
  float impsum = 0.0f;
  for (int b = 0; b < B_; ++b) {
    float v = 0.0f;
    for (int c = 0; c < APART; ++c) v += ws[WS_IMP + c * 512 + b * 64 + lane];
    float sfull = wave_sum64(v);
    float mean = sfull * (1.0f / 64.0f);
    float d = v - mean;
    float ss = wave_sum64(d * d);
    impsum += (ss / 63.0f) / (mean * mean);
  }
  float importance = impsum * (1.0f / (float)B_);

  float sp1 = 0.0f, sp2 = 0.0f;
  if (lane < APART) { sp1 = ws[WS_SP + lane * 2]; sp2 = ws[WS_SP + lane * 2 + 1]; }
  sp1 = wave_sum64(sp1);
  sp2 = wave_sum64(sp2);
  const float N = (float)(S_ * E_);
  float meanp = sp1 / N;
  float varp = sp2 / N - meanp * meanp;
  float load = varp / (meanp * meanp);

  float sgn = 0.0f, cnt = 0.0f;
  for (int c = 0; c < APART; ++c) {
    sgn += ws[WS_SGN + c * 64 + lane];
    cnt += ws[WS_CNT + c * 64 + lane];
  }
  const float inv_rows = 1.0f / (float)(B_ * S_);
  float te = (cnt * inv_rows) * (sgn * inv_rows);
  float gs = wave_sum64(te) * (float)E_;

  if (lane == 0) {
    out[OUT_GATES + 0] = importance + load;  // aux (GSHARD_W = 0)
    out[OUT_GATES + 1] = gs;
    out[OUT_GATES + 2] = importance;
    out[OUT_GATES + 3] = load;
  }
}

extern "C" void kernel_launch(void* const* d_in, const int* in_sizes, int n_in,
                              void* d_out, int out_size, void* d_ws, size_t ws_size,
                              hipStream_t stream) {
  (void)in_sizes; (void)n_in; (void)out_size; (void)ws_size;
  const float* X     = (const float*)d_in[0];
  const float* noise = (const float*)d_in[1];
  const float* gamma = (const float*)d_in[2];
  const float* beta  = (const float*)d_in[3];
  const float* W     = (const float*)d_in[4];
  float* out = (float*)d_out;
  float* ws  = (float*)d_ws;

  router_prep<<<dim3(E_ + 8), dim3(256), 0, stream>>>(W, gamma, beta, ws);
  router_main<<<dim3(S_ * B_ / 16), dim3(256), 0, stream>>>(X, noise, out, ws);
  router_final<<<dim3(1), dim3(64), 0, stream>>>(ws, out);
}

// Round 4
// 84.623 us; speedup vs baseline: 2.0248x; 1.0066x over previous
//
#include <hip/hip_runtime.h>
#include <hip/hip_bf16.h>
#include <math.h>

// NoisyTopExpertsPerItemRouter: B=8,S=4096,D=1024,E=64,K=2
#define B_ 8
#define S_ 4096
#define D_ 1024
#define E_ 64
#define NOISE_STD 0.015625f     // max(1/64, 1e-6)
#define INV_NOISE_STD 64.0f
#define OUT_GATES (B_ * S_ * E_)   // 2097152
#define APART 32                   // striped global accumulator copies

typedef __attribute__((ext_vector_type(8))) short short8;
typedef __attribute__((ext_vector_type(4))) float f32x4;

// workspace layout (float offsets)
// [0 .. 32768): Wg as bf16 [64][1024] (ushort)
#define WS_GW   32768                    // GW[64]
#define WS_BW   32832                    // BW[64]
#define WS_IMP  32896                    // APART x [8][64]
#define WS_SGN  (WS_IMP + APART * 512)   // APART x [64]
#define WS_CNT  (WS_SGN + APART * 64)    // APART x [64]
#define WS_SP   (WS_CNT + APART * 64)    // APART x [2]
#define WS_NACC (APART * 512 + APART * 64 + APART * 64 + APART * 2)

__device__ __forceinline__ float wave_sum64(float v) {
#pragma unroll
  for (int o = 32; o > 0; o >>= 1) v += __shfl_xor(v, o);
  return v;
}

// ---------------- prep: Wg(bf16) = gamma*W, GW/BW reductions, zero accums ----
__global__ void router_prep(const float* __restrict__ W,
                            const float* __restrict__ gamma,
                            const float* __restrict__ beta,
                            float* __restrict__ ws) {
  if (blockIdx.x >= E_) {
    const int z = blockIdx.x - E_;   // 0..7
    for (int i = z * 256 + threadIdx.x; i < WS_NACC; i += 8 * 256)
      ws[WS_IMP + i] = 0.0f;
    return;
  }
  const int e = blockIdx.x;
  unsigned short* wgb = (unsigned short*)ws;
  float gw = 0.0f, bw = 0.0f;
  for (int d = threadIdx.x; d < D_; d += 256) {
    float wv = W[e * D_ + d];
    float pv = gamma[d] * wv;
    union { __hip_bfloat16 h; unsigned short u; } cv;
    cv.h = __float2bfloat16(pv);
    wgb[e * D_ + d] = cv.u;
    gw += __bfloat162float(cv.h);   // sum of ROUNDED values (consistency)
    bw += beta[d] * wv;
  }
  __shared__ float sred[8];
  gw = wave_sum64(gw);
  bw = wave_sum64(bw);
  const int w = threadIdx.x >> 6, lane = threadIdx.x & 63;
  if (lane == 0) { sred[w] = gw; sred[4 + w] = bw; }
  __syncthreads();
  if (threadIdx.x == 0) {
    ws[WS_GW + e] = sred[0] + sred[1] + sred[2] + sred[3];
    ws[WS_BW + e] = sred[4] + sred[5] + sred[6] + sred[7];
  }
}

// ---------------- main: K-split-4 bf16 MFMA + register-transposed epilogue --
// block = 256 thr = 4 waves; block owns 16 rows: r in [0,16), b=r&7, sl=r>>3,
// s = 2*blockIdx + sl. Wave w = K-chunk [256w,256w+256) for ALL 16 rows.
// Epilogue: wave 0 only, lane = (row rl = lane&15, expert-quarter q = lane>>4),
// 16 logits per lane in registers; reductions = 15 reg-ops + 2 shfl steps.
__global__ void __launch_bounds__(256, 8)
router_main(const float* __restrict__ X, const float* __restrict__ noise,
            float* __restrict__ out, float* __restrict__ ws) {
  __shared__ __align__(16) float unbuf[3 * 16 * 68];   // 13056B union region
  __shared__ float Lg[16 * 68];                        // logits [16][68]
  __shared__ float svp[4][16], sv2p[4][16];
  __shared__ float cntl[64];
  __shared__ float red4[4];

  f32x4* Pp = (f32x4*)unbuf;            // [4 chains][3 srcs][64 lanes] = 12288B
  float* gcl = unbuf;                   // [16][68] clean gates
  float* gnl = unbuf + 1088;            // [16][68] noisy gates
  float* pl  = unbuf + 2176;            // [16][68] p values

  const int t = threadIdx.x;
  const int w = t >> 6, lane = t & 63;
  const int lrow = lane & 15, kh = lane >> 4;
  const int s0 = blockIdx.x * 2;

  // ---- GEMM phase (identical geometry to round 3) ----
  const int b_mf = lrow & 7, sl_mf = lrow >> 3;
  const int wko = w * 256 + kh * 8;
  const float* __restrict__ xp =
      X + ((size_t)b_mf * S_ + (size_t)(s0 + sl_mf)) * D_ + wko;
  const unsigned short* __restrict__ wgb = (const unsigned short*)ws;
  const unsigned short* __restrict__ bp0 = wgb + (0  + lrow) * D_ + wko;
  const unsigned short* __restrict__ bp1 = wgb + (16 + lrow) * D_ + wko;
  const unsigned short* __restrict__ bp2 = wgb + (32 + lrow) * D_ + wko;
  const unsigned short* __restrict__ bp3 = wgb + (48 + lrow) * D_ + wko;

  float sv = 0.0f, sv2 = 0.0f;
  f32x4 acc0 = {0.f, 0.f, 0.f, 0.f};
  f32x4 acc1 = {0.f, 0.f, 0.f, 0.f};
  f32x4 acc2 = {0.f, 0.f, 0.f, 0.f};
  f32x4 acc3 = {0.f, 0.f, 0.f, 0.f};

#pragma unroll 4
  for (int k0 = 0; k0 < 256; k0 += 32) {
    float4 a0 = *(const float4*)(xp + k0);
    float4 a1 = *(const float4*)(xp + k0 + 4);
    short8 b0 = *(const short8*)(bp0 + k0);
    short8 b1 = *(const short8*)(bp1 + k0);
    short8 b2 = *(const short8*)(bp2 + k0);
    short8 b3 = *(const short8*)(bp3 + k0);

    sv += (a0.x + a0.y) + (a0.z + a0.w) + (a1.x + a1.y) + (a1.z + a1.w);
    sv2 = fmaf(a0.x, a0.x, sv2); sv2 = fmaf(a0.y, a0.y, sv2);
    sv2 = fmaf(a0.z, a0.z, sv2); sv2 = fmaf(a0.w, a0.w, sv2);
    sv2 = fmaf(a1.x, a1.x, sv2); sv2 = fmaf(a1.y, a1.y, sv2);
    sv2 = fmaf(a1.z, a1.z, sv2); sv2 = fmaf(a1.w, a1.w, sv2);

    union { short8 s; __hip_bfloat162 h[4]; } u;
    u.h[0] = __float22bfloat162_rn(make_float2(a0.x, a0.y));
    u.h[1] = __float22bfloat162_rn(make_float2(a0.z, a0.w));
    u.h[2] = __float22bfloat162_rn(make_float2(a1.x, a1.y));
    u.h[3] = __float22bfloat162_rn(make_float2(a1.z, a1.w));

    acc0 = __builtin_amdgcn_mfma_f32_16x16x32_bf16(u.s, b0, acc0, 0, 0, 0);
    acc1 = __builtin_amdgcn_mfma_f32_16x16x32_bf16(u.s, b1, acc1, 0, 0, 0);
    acc2 = __builtin_amdgcn_mfma_f32_16x16x32_bf16(u.s, b2, acc2, 0, 0, 0);
    acc3 = __builtin_amdgcn_mfma_f32_16x16x32_bf16(u.s, b3, acc3, 0, 0, 0);
  }

  // per-row LN stats partial: combine the 4 kh lanes of each row
  sv  += __shfl_xor(sv, 16);  sv  += __shfl_xor(sv, 32);
  sv2 += __shfl_xor(sv2, 16); sv2 += __shfl_xor(sv2, 32);
  if (lane < 16) { svp[w][lane] = sv; sv2p[w][lane] = sv2; }

  // publish partials for the 3 chains we don't own (chain c combined by wave c)
  if (w != 0) Pp[(0 * 3 + (w - 1)) * 64 + lane] = acc0;
  if (w != 1) Pp[(1 * 3 + (w - (w > 1))) * 64 + lane] = acc1;
  if (w != 2) Pp[(2 * 3 + (w - (w > 2))) * 64 + lane] = acc2;
  if (w != 3) Pp[(3 * 3 + w) * 64 + lane] = acc3;
  __syncthreads();

  // wave w combines chain w: own acc_w (K-chunk w) + 3 published partials
  f32x4 mine = (w == 0) ? acc0 : (w == 1) ? acc1 : (w == 2) ? acc2 : acc3;
  f32x4 asum = mine + Pp[(w * 3 + 0) * 64 + lane] +
               Pp[(w * 3 + 1) * 64 + lane] + Pp[(w * 3 + 2) * 64 + lane];

  const float svr  = (svp[0][lrow] + svp[1][lrow]) + (svp[2][lrow] + svp[3][lrow]);
  const float sv2r = (sv2p[0][lrow] + sv2p[1][lrow]) + (sv2p[2][lrow] + sv2p[3][lrow]);
  float mu = svr * (1.0f / (float)D_);
  float var = sv2r * (1.0f / (float)D_) - mu * mu;
  float rs = rsqrtf(var + 1e-5f);
  const float gwv = ws[WS_GW + 16 * w + lrow];
  const float bwv = ws[WS_BW + 16 * w + lrow];

  // C/D layout: col(expert-in-tile)=lane&15, row=(lane>>4)*4+i  [m89-verified]
#pragma unroll
  for (int i = 0; i < 4; i++) {
    const int rloc = kh * 4 + i;
    const float mui = __shfl(mu, kh * 4 + i);
    const float rsi = __shfl(rs, kh * 4 + i);
    Lg[rloc * 68 + 16 * w + lrow] = rsi * (asum[i] - mui * gwv) + bwv;
  }
  if (t < 64) cntl[t] = 0.0f;
  __syncthreads();

  // ---- epilogue: wave 0 only; lane = (rl, q); 16 experts/lane in registers ----
  if (w == 0) {
    const int q = kh, rl = lrow;
    const int b = rl & 7, sl = rl >> 3;
    const int s = s0 + sl;
    const float* Lr = Lg + rl * 68 + q * 16;

    // noisy logits ln_[16] (only persistent array; l re-read from LDS)
    float ln_[16];
    {
      const float* nzp = noise + ((size_t)b * S_ + s) * E_ + q * 16;
#pragma unroll
      for (int jj = 0; jj < 4; jj++) {
        float4 nv = *(const float4*)(nzp + 4 * jj);
        float4 lv = *(const float4*)(Lr + 4 * jj);
        ln_[4 * jj + 0] = fmaf(NOISE_STD, nv.x, lv.x);
        ln_[4 * jj + 1] = fmaf(NOISE_STD, nv.y, lv.y);
        ln_[4 * jj + 2] = fmaf(NOISE_STD, nv.z, lv.z);
        ln_[4 * jj + 3] = fmaf(NOISE_STD, nv.w, lv.w);
      }
    }
    // combined max + secondmax of noisy logits (m1 also shifts clean softmax)
    float m1 = ln_[0], m2 = -INFINITY;
#pragma unroll
    for (int j = 1; j < 16; j++) {
      float x = ln_[j];
      m2 = fmaxf(m2, fminf(m1, x));
      m1 = fmaxf(m1, x);
    }
#pragma unroll
    for (int o = 16; o <= 32; o <<= 1) {
      float o1 = __shfl_xor(m1, o), o2 = __shfl_xor(m2, o);
      m2 = fmaxf(fmaxf(m2, o2), fminf(m1, o1));
      m1 = fmaxf(m1, o1);
    }
    // denominators (clean l re-read from LDS; shift by m1 valid for both)
    float sg = 0.0f, sn = 0.0f;
#pragma unroll
    for (int jj = 0; jj < 4; jj++) {
      float4 lv = *(const float4*)(Lr + 4 * jj);
      sg += __expf(lv.x - m1) + __expf(lv.y - m1) +
            __expf(lv.z - m1) + __expf(lv.w - m1);
      sn += __expf(ln_[4 * jj + 0] - m1) + __expf(ln_[4 * jj + 1] - m1) +
            __expf(ln_[4 * jj + 2] - m1) + __expf(ln_[4 * jj + 3] - m1);
    }
    sg += __shfl_xor(sg, 16); sg += __shfl_xor(sg, 32);
    sn += __shfl_xor(sn, 16); sn += __shfl_xor(sn, 32);
    const float rg = 1.0f / sg, rn = 1.0f / sn;

    float* outp = out + ((size_t)b * S_ + s) * E_ + q * 16;
#pragma unroll
    for (int jj = 0; jj < 4; jj++) {
      float4 lv = *(const float4*)(Lr + 4 * jj);
      float4 gcv, gnv, pv;
      {
        gcv.x = __expf(lv.x - m1) * rg;  gcv.y = __expf(lv.y - m1) * rg;
        gcv.z = __expf(lv.z - m1) * rg;  gcv.w = __expf(lv.w - m1) * rg;
        gnv.x = __expf(ln_[4 * jj + 0] - m1) * rn;
        gnv.y = __expf(ln_[4 * jj + 1] - m1) * rn;
        gnv.z = __expf(ln_[4 * jj + 2] - m1) * rn;
        gnv.w = __expf(ln_[4 * jj + 3] - m1) * rn;
        float z0 = fminf(fmaxf((m2 - lv.x) * INV_NOISE_STD, -10.f), 10.f);
        float z1 = fminf(fmaxf((m2 - lv.y) * INV_NOISE_STD, -10.f), 10.f);
        float z2 = fminf(fmaxf((m2 - lv.z) * INV_NOISE_STD, -10.f), 10.f);
        float z3 = fminf(fmaxf((m2 - lv.w) * INV_NOISE_STD, -10.f), 10.f);
        pv.x = 0.5f * (1.0f + erff(z0 * 0.70710678118654752f));
        pv.y = 0.5f * (1.0f + erff(z1 * 0.70710678118654752f));
        pv.z = 0.5f * (1.0f + erff(z2 * 0.70710678118654752f));
        pv.w = 0.5f * (1.0f + erff(z3 * 0.70710678118654752f));
      }
      *(float4*)(outp + 4 * jj) = gnv;
      *(float4*)(gcl + rl * 68 + q * 16 + 4 * jj) = gcv;
      *(float4*)(gnl + rl * 68 + q * 16 + 4 * jj) = gnv;
      *(float4*)(pl  + rl * 68 + q * 16 + 4 * jj) = pv;
    }
    // top-1 count via equality (ties vanishingly rare; softmax is monotone)
#pragma unroll
    for (int j = 0; j < 16; j++)
      if (ln_[j] == m1) atomicAdd(&cntl[q * 16 + j], 1.0f);
  }
  __syncthreads();

  // ---- phase 2: block-level reductions -> striped global accumulators ----
  const int pc = blockIdx.x & (APART - 1);
  {
    // importance: (b,e) pairs; each thread does 2
    int b0i = t >> 6, e0i = t & 63;
    float v0 = gcl[b0i * 68 + e0i] + gcl[(8 + b0i) * 68 + e0i];
    atomicAdd(&ws[WS_IMP + pc * 512 + t], v0);
    int p1 = t + 256;
    int b1i = p1 >> 6, e1i = p1 & 63;
    float v1 = gcl[b1i * 68 + e1i] + gcl[(8 + b1i) * 68 + e1i];
    atomicAdd(&ws[WS_IMP + pc * 512 + p1], v1);
  }
  if (t < 64) {
    float sgn = 0.0f;
#pragma unroll
    for (int r = 0; r < 16; r++) sgn += gnl[r * 68 + t];
    atomicAdd(&ws[WS_SGN + pc * 64 + t], sgn);
  } else if (t < 128) {
    atomicAdd(&ws[WS_CNT + pc * 64 + (t - 64)], cntl[t - 64]);
  } else {
    const int idx = t - 128;            // [0,128): sl = idx>>6, e = idx&63
    const int slc = idx >> 6, e = idx & 63;
    float P = 0.0f;
#pragma unroll
    for (int b = 0; b < 8; b++) P += pl[(slc * 8 + b) * 68 + e];
    float c1 = P * 0.125f;
    float c2 = c1 * c1;
    c1 = wave_sum64(c1);
    c2 = wave_sum64(c2);
    if (lane == 0) { red4[(w - 2) * 2] = c1; red4[(w - 2) * 2 + 1] = c2; }
  }
  __syncthreads();
  if (t == 0) {
    atomicAdd(&ws[WS_SP + pc * 2 + 0], red4[0] + red4[2]);
    atomicAdd(&ws[WS_SP + pc * 2 + 1], red4[1] + red4[3]);
  }
}

// ---------------- finalize: reduce APART copies, 3 scalar losses ------------
__global__ void router_final(const float* __restrict__ ws, float* __restrict__ out) {
  const int lane = threadIdx.x;  // 64 threads = 1 wave
  float impsum = 0.0f;
  for (int b = 0; b < B_; ++b) {
    float v = 0.0f;
    for (int c = 0; c < APART; ++c) v += ws[WS_IMP + c * 512 + b * 64 + lane];
    float sfull = wave_sum64(v);
    float mean = sfull * (1.0f / 64.0f);
    float d = v - mean;
    float ss = wave_sum64(d * d);
    impsum += (ss / 63.0f) / (mean * mean);
  }
  float importance = impsum * (1.0f / (float)B_);

  float sp1 = 0.0f, sp2 = 0.0f;
  if (lane < APART) { sp1 = ws[WS_SP + lane * 2]; sp2 = ws[WS_SP + lane * 2 + 1]; }
  sp1 = wave_sum64(sp1);
  sp2 = wave_sum64(sp2);
  const float N = (float)(S_ * E_);
  float meanp = sp1 / N;
  float varp = sp2 / N - meanp * meanp;
  float load = varp / (meanp * meanp);

  float sgn = 0.0f, cnt = 0.0f;
  for (int c = 0; c < APART; ++c) {
    sgn += ws[WS_SGN + c * 64 + lane];
    cnt += ws[WS_CNT + c * 64 + lane];
  }
  const float inv_rows = 1.0f / (float)(B_ * S_);
  float te = (cnt * inv_rows) * (sgn * inv_rows);
  float gs = wave_sum64(te) * (float)E_;

  if (lane == 0) {
    out[OUT_GATES + 0] = importance + load;  // aux (GSHARD_W = 0)
    out[OUT_GATES + 1] = gs;
    out[OUT_GATES + 2] = importance;
    out[OUT_GATES + 3] = load;
  }
}

extern "C" void kernel_launch(void* const* d_in, const int* in_sizes, int n_in,
                              void* d_out, int out_size, void* d_ws, size_t ws_size,
                              hipStream_t stream) {
  (void)in_sizes; (void)n_in; (void)out_size; (void)ws_size;
  const float* X     = (const float*)d_in[0];
  const float* noise = (const float*)d_in[1];
  const float* gamma = (const float*)d_in[2];
  const float* beta  = (const float*)d_in[3];
  const float* W     = (const float*)d_in[4];
  float* out = (float*)d_out;
  float* ws  = (float*)d_ws;

  router_prep<<<dim3(E_ + 8), dim3(256), 0, stream>>>(W, gamma, beta, ws);
  router_main<<<dim3(S_ / 2), dim3(256), 0, stream>>>(X, noise, out, ws);
  router_final<<<dim3(1), dim3(64), 0, stream>>>(ws, out);
}

// Round 5
// 84.047 us; speedup vs baseline: 2.0387x; 1.0069x over previous
//
#include <hip/hip_runtime.h>
#include <hip/hip_bf16.h>
#include <math.h>

// NoisyTopExpertsPerItemRouter: B=8,S=4096,D=1024,E=64,K=2
#define B_ 8
#define S_ 4096
#define D_ 1024
#define E_ 64
#define NOISE_STD 0.015625f     // max(1/64, 1e-6)
#define INV_NOISE_STD 64.0f
#define OUT_GATES (B_ * S_ * E_)   // 2097152
#define APART 32                   // striped global accumulator copies

typedef __attribute__((ext_vector_type(8))) short short8;
typedef __attribute__((ext_vector_type(4))) float f32x4;

// workspace layout (float offsets)
// [0 .. 32768): Wg as bf16 [64][1024] (ushort)
#define WS_GW   32768                    // GW[64]
#define WS_BW   32832                    // BW[64]
#define WS_IMP  32896                    // APART x [8][64]
#define WS_SGN  (WS_IMP + APART * 512)   // APART x [64]
#define WS_CNT  (WS_SGN + APART * 64)    // APART x [64]
#define WS_SP   (WS_CNT + APART * 64)    // APART x [2]
#define WS_NACC (APART * 512 + APART * 64 + APART * 64 + APART * 2)

__device__ __forceinline__ float wave_sum64(float v) {
#pragma unroll
  for (int o = 32; o > 0; o >>= 1) v += __shfl_xor(v, o);
  return v;
}

// ---------------- prep: Wg(bf16) = gamma*W, GW/BW reductions, zero accums ----
__global__ void router_prep(const float* __restrict__ W,
                            const float* __restrict__ gamma,
                            const float* __restrict__ beta,
                            float* __restrict__ ws) {
  if (blockIdx.x >= E_) {
    const int z = blockIdx.x - E_;   // 0..7
    for (int i = z * 256 + threadIdx.x; i < WS_NACC; i += 8 * 256)
      ws[WS_IMP + i] = 0.0f;
    return;
  }
  const int e = blockIdx.x;
  unsigned short* wgb = (unsigned short*)ws;
  float gw = 0.0f, bw = 0.0f;
  for (int d = threadIdx.x; d < D_; d += 256) {
    float wv = W[e * D_ + d];
    float pv = gamma[d] * wv;
    union { __hip_bfloat16 h; unsigned short u; } cv;
    cv.h = __float2bfloat16(pv);
    wgb[e * D_ + d] = cv.u;
    gw += __bfloat162float(cv.h);   // sum of ROUNDED values (consistency)
    bw += beta[d] * wv;
  }
  __shared__ float sred[8];
  gw = wave_sum64(gw);
  bw = wave_sum64(bw);
  const int w = threadIdx.x >> 6, lane = threadIdx.x & 63;
  if (lane == 0) { sred[w] = gw; sred[4 + w] = bw; }
  __syncthreads();
  if (threadIdx.x == 0) {
    ws[WS_GW + e] = sred[0] + sred[1] + sred[2] + sred[3];
    ws[WS_BW + e] = sred[4] + sred[5] + sred[6] + sred[7];
  }
}

// ---------------- main: LDS-staged coalesced X, wave = 16-expert tile -------
// block = 256 thr = 4 waves; block owns 16 rows (r: b=r&7, sl=r>>3, s=2*bid+sl).
// K-loop: 16 steps of 64 k's; X tile [16][64]->pad68 double-buffered in LDS,
// staged block-wide with 256B-contiguous per-row loads. Wave w computes
// experts [16w,16w+16) over FULL K (no partial-acc exchange). All waves read
// the same A fragments -> LN stats free in every wave.
__global__ void __launch_bounds__(256, 8)
router_main(const float* __restrict__ X, const float* __restrict__ noise,
            float* __restrict__ out, float* __restrict__ ws) {
  __shared__ __align__(16) float Xl[2][1088];   // 2 x [16][68] f32 = 8704B
  __shared__ __align__(16) float Lg[1088];      // [16][68] logits
  __shared__ float cntl[64];
  __shared__ float red4[4];
  float* gcl = Xl[0];   // epilogue aliases (GEMM reads done by then)
  float* gnl = Xl[1];
  float* pl  = Lg;      // per-lane read-then-write -> safe alias

  const int t = threadIdx.x;
  const int w = t >> 6, lane = t & 63;
  const int lrow = lane & 15, kh = lane >> 4;
  const int s0 = blockIdx.x * 2;

  // staging mapping: thread t -> row t>>4, cols (t&15)*4..+4 (256B/row chunks)
  const int r_t = t >> 4, c_t = (t & 15) * 4;
  const float* __restrict__ xstage =
      X + ((size_t)(r_t & 7) * S_ + (size_t)(s0 + (r_t >> 3))) * D_ + c_t;
  const int ldso = r_t * 68 + c_t;

  // B: wave w experts [16w,16w+16); lane&15 = expert-in-tile, kh = k-slice
  const unsigned short* __restrict__ bp =
      (const unsigned short*)ws + (16 * w + lrow) * D_ + kh * 8;

  const float gwv = ws[WS_GW + 16 * w + lrow];
  const float bwv = ws[WS_BW + 16 * w + lrow];

  // prologue: steps 0,1 into regs; step 0 into LDS buf 0
  float4 rE = *(const float4*)(xstage);         // even steps
  float4 rO = *(const float4*)(xstage + 64);    // odd steps
  *(float4*)(&Xl[0][ldso]) = rE;

  float sv = 0.0f, sv2 = 0.0f;
  f32x4 acc = {0.f, 0.f, 0.f, 0.f};

#pragma unroll
  for (int s = 0; s < 16; ++s) {
    __syncthreads();                 // buf[s&1] staged; buf[(s+1)&1] free
    if (s + 2 < 16) {                // prefetch step s+2 into freed reg
      if (s & 1) rO = *(const float4*)(xstage + (s + 2) * 64);
      else       rE = *(const float4*)(xstage + (s + 2) * 64);
    }
    const float* xb = Xl[s & 1];
#pragma unroll
    for (int ks = 0; ks < 2; ++ks) {
      const float* fr = xb + lrow * 68 + ks * 32 + kh * 8;
      float4 a0 = *(const float4*)(fr);
      float4 a1 = *(const float4*)(fr + 4);
      short8 bv = *(const short8*)(bp + s * 64 + ks * 32);

      sv += (a0.x + a0.y) + (a0.z + a0.w) + (a1.x + a1.y) + (a1.z + a1.w);
      sv2 = fmaf(a0.x, a0.x, sv2); sv2 = fmaf(a0.y, a0.y, sv2);
      sv2 = fmaf(a0.z, a0.z, sv2); sv2 = fmaf(a0.w, a0.w, sv2);
      sv2 = fmaf(a1.x, a1.x, sv2); sv2 = fmaf(a1.y, a1.y, sv2);
      sv2 = fmaf(a1.z, a1.z, sv2); sv2 = fmaf(a1.w, a1.w, sv2);

      union { short8 s8; __hip_bfloat162 h[4]; } u;
      u.h[0] = __float22bfloat162_rn(make_float2(a0.x, a0.y));
      u.h[1] = __float22bfloat162_rn(make_float2(a0.z, a0.w));
      u.h[2] = __float22bfloat162_rn(make_float2(a1.x, a1.y));
      u.h[3] = __float22bfloat162_rn(make_float2(a1.z, a1.w));
      acc = __builtin_amdgcn_mfma_f32_16x16x32_bf16(u.s8, bv, acc, 0, 0, 0);
    }
    if (s + 1 < 16) {                // stage step s+1 into the other buffer
      float4 wv = ((s + 1) & 1) ? rO : rE;
      *(float4*)(&Xl[(s + 1) & 1][ldso]) = wv;
    }
  }

  // full-row LN stats (every wave saw all fragments): combine 4 kh lanes
  sv  += __shfl_xor(sv, 16);  sv  += __shfl_xor(sv, 32);
  sv2 += __shfl_xor(sv2, 16); sv2 += __shfl_xor(sv2, 32);
  float mu = sv * (1.0f / (float)D_);
  float var = sv2 * (1.0f / (float)D_) - mu * mu;
  float rs = rsqrtf(var + 1e-5f);

  // C/D layout: col(expert-in-tile)=lane&15, row=(lane>>4)*4+i  [m89-verified]
#pragma unroll
  for (int i = 0; i < 4; i++) {
    const float mui = __shfl(mu, kh * 4 + i);
    const float rsi = __shfl(rs, kh * 4 + i);
    Lg[(kh * 4 + i) * 68 + 16 * w + lrow] = rsi * (acc[i] - mui * gwv) + bwv;
  }
  if (t < 64) cntl[t] = 0.0f;
  __syncthreads();

  // ---- epilogue: all 4 waves; wave w rows 4w..4w+3; lane=(rr,j), 4 experts --
  {
    const int rr = lane >> 4, j = lane & 15;
    const int r = w * 4 + rr;
    const int b = r & 7, sl = r >> 3;
    const int s = s0 + sl;
    float4 lv = *(const float4*)(Lg + r * 68 + 4 * j);
    float4 nv = *(const float4*)(noise + ((size_t)b * S_ + s) * E_ + 4 * j);
    float ln0 = fmaf(NOISE_STD, nv.x, lv.x);
    float ln1 = fmaf(NOISE_STD, nv.y, lv.y);
    float ln2 = fmaf(NOISE_STD, nv.z, lv.z);
    float ln3 = fmaf(NOISE_STD, nv.w, lv.w);

    // combined max+secondmax of noisy logits (m1 also shifts clean softmax)
    float m1 = ln0, m2 = -INFINITY;
    m2 = fmaxf(m2, fminf(m1, ln1)); m1 = fmaxf(m1, ln1);
    m2 = fmaxf(m2, fminf(m1, ln2)); m1 = fmaxf(m1, ln2);
    m2 = fmaxf(m2, fminf(m1, ln3)); m1 = fmaxf(m1, ln3);
#pragma unroll
    for (int o = 1; o <= 8; o <<= 1) {
      float o1 = __shfl_xor(m1, o), o2 = __shfl_xor(m2, o);
      m2 = fmaxf(fmaxf(m2, o2), fminf(m1, o1));
      m1 = fmaxf(m1, o1);
    }
    float ec0 = __expf(lv.x - m1), ec1 = __expf(lv.y - m1);
    float ec2 = __expf(lv.z - m1), ec3 = __expf(lv.w - m1);
    float en0 = __expf(ln0 - m1), en1 = __expf(ln1 - m1);
    float en2 = __expf(ln2 - m1), en3 = __expf(ln3 - m1);
    float sg = (ec0 + ec1) + (ec2 + ec3);
    float sn = (en0 + en1) + (en2 + en3);
#pragma unroll
    for (int o = 1; o <= 8; o <<= 1) {
      sg += __shfl_xor(sg, o);
      sn += __shfl_xor(sn, o);
    }
    const float rg = 1.0f / sg, rn = 1.0f / sn;
    float4 gnv = { en0 * rn, en1 * rn, en2 * rn, en3 * rn };
    float4 gcv = { ec0 * rg, ec1 * rg, ec2 * rg, ec3 * rg };
    float z0 = fminf(fmaxf((m2 - lv.x) * INV_NOISE_STD, -10.f), 10.f);
    float z1 = fminf(fmaxf((m2 - lv.y) * INV_NOISE_STD, -10.f), 10.f);
    float z2 = fminf(fmaxf((m2 - lv.z) * INV_NOISE_STD, -10.f), 10.f);
    float z3 = fminf(fmaxf((m2 - lv.w) * INV_NOISE_STD, -10.f), 10.f);
    float4 pv = { 0.5f * (1.0f + erff(z0 * 0.70710678118654752f)),
                  0.5f * (1.0f + erff(z1 * 0.70710678118654752f)),
                  0.5f * (1.0f + erff(z2 * 0.70710678118654752f)),
                  0.5f * (1.0f + erff(z3 * 0.70710678118654752f)) };

    *(float4*)(out + ((size_t)b * S_ + s) * E_ + 4 * j) = gnv;
    *(float4*)(gnl + r * 68 + 4 * j) = gnv;
    *(float4*)(gcl + r * 68 + 4 * j) = gcv;
    *(float4*)(pl  + r * 68 + 4 * j) = pv;
    // top-1 count via equality (ties vanishingly rare; softmax is monotone)
    if (ln0 == m1) atomicAdd(&cntl[4 * j + 0], 1.0f);
    if (ln1 == m1) atomicAdd(&cntl[4 * j + 1], 1.0f);
    if (ln2 == m1) atomicAdd(&cntl[4 * j + 2], 1.0f);
    if (ln3 == m1) atomicAdd(&cntl[4 * j + 3], 1.0f);
  }
  __syncthreads();

  // ---- phase 2: block-level reductions -> striped global accumulators ----
  const int pc = blockIdx.x & (APART - 1);
  {
    int b0i = t >> 6, e0i = t & 63;
    float v0 = gcl[b0i * 68 + e0i] + gcl[(8 + b0i) * 68 + e0i];
    atomicAdd(&ws[WS_IMP + pc * 512 + t], v0);
    int p1 = t + 256;
    int b1i = p1 >> 6, e1i = p1 & 63;
    float v1 = gcl[b1i * 68 + e1i] + gcl[(8 + b1i) * 68 + e1i];
    atomicAdd(&ws[WS_IMP + pc * 512 + p1], v1);
  }
  if (t < 64) {
    float sgn = 0.0f;
#pragma unroll
    for (int r = 0; r < 16; r++) sgn += gnl[r * 68 + t];
    atomicAdd(&ws[WS_SGN + pc * 64 + t], sgn);
  } else if (t < 128) {
    atomicAdd(&ws[WS_CNT + pc * 64 + (t - 64)], cntl[t - 64]);
  } else {
    const int idx = t - 128;            // [0,128): sl = idx>>6, e = idx&63
    const int slc = idx >> 6, e = idx & 63;
    float P = 0.0f;
#pragma unroll
    for (int b = 0; b < 8; b++) P += pl[(slc * 8 + b) * 68 + e];
    float c1 = P * 0.125f;
    float c2 = c1 * c1;
    c1 = wave_sum64(c1);
    c2 = wave_sum64(c2);
    if (lane == 0) { red4[(w - 2) * 2] = c1; red4[(w - 2) * 2 + 1] = c2; }
  }
  __syncthreads();
  if (t == 0) {
    atomicAdd(&ws[WS_SP + pc * 2 + 0], red4[0] + red4[2]);
    atomicAdd(&ws[WS_SP + pc * 2 + 1], red4[1] + red4[3]);
  }
}

// ---------------- finalize: reduce APART copies, 3 scalar losses ------------
__global__ void router_final(const float* __restrict__ ws, float* __restrict__ out) {
  const int lane = threadIdx.x;  // 64 threads = 1 wave
  float impsum = 0.0f;
  for (int b = 0; b < B_; ++b) {
    float v = 0.0f;
    for (int c = 0; c < APART; ++c) v += ws[WS_IMP + c * 512 + b * 64 + lane];
    float sfull = wave_sum64(v);
    float mean = sfull * (1.0f / 64.0f);
    float d = v - mean;
    float ss = wave_sum64(d * d);
    impsum += (ss / 63.0f) / (mean * mean);
  }
  float importance = impsum * (1.0f / (float)B_);

  float sp1 = 0.0f, sp2 = 0.0f;
  if (lane < APART) { sp1 = ws[WS_SP + lane * 2]; sp2 = ws[WS_SP + lane * 2 + 1]; }
  sp1 = wave_sum64(sp1);
  sp2 = wave_sum64(sp2);
  const float N = (float)(S_ * E_);
  float meanp = sp1 / N;
  float varp = sp2 / N - meanp * meanp;
  float load = varp / (meanp * meanp);

  float sgn = 0.0f, cnt = 0.0f;
  for (int c = 0; c < APART; ++c) {
    sgn += ws[WS_SGN + c * 64 + lane];
    cnt += ws[WS_CNT + c * 64 + lane];
  }
  const float inv_rows = 1.0f / (float)(B_ * S_);
  float te = (cnt * inv_rows) * (sgn * inv_rows);
  float gs = wave_sum64(te) * (float)E_;

  if (lane == 0) {
    out[OUT_GATES + 0] = importance + load;  // aux (GSHARD_W = 0)
    out[OUT_GATES + 1] = gs;
    out[OUT_GATES + 2] = importance;
    out[OUT_GATES + 3] = load;
  }
}

extern "C" void kernel_launch(void* const* d_in, const int* in_sizes, int n_in,
                              void* d_out, int out_size, void* d_ws, size_t ws_size,
                              hipStream_t stream) {
  (void)in_sizes; (void)n_in; (void)out_size; (void)ws_size;
  const float* X     = (const float*)d_in[0];
  const float* noise = (const float*)d_in[1];
  const float* gamma = (const float*)d_in[2];
  const float* beta  = (const float*)d_in[3];
  const float* W     = (const float*)d_in[4];
  float* out = (float*)d_out;
  float* ws  = (float*)d_ws;

  router_prep<<<dim3(E_ + 8), dim3(256), 0, stream>>>(W, gamma, beta, ws);
  router_main<<<dim3(S_ / 2), dim3(256), 0, stream>>>(X, noise, out, ws);
  router_final<<<dim3(1), dim3(64), 0, stream>>>(ws, out);
}

// Round 6
// 83.093 us; speedup vs baseline: 2.0620x; 1.0115x over previous
//
#include <hip/hip_runtime.h>
#include <hip/hip_bf16.h>
#include <math.h>

// NoisyTopExpertsPerItemRouter: B=8,S=4096,D=1024,E=64,K=2
#define B_ 8
#define S_ 4096
#define D_ 1024
#define E_ 64
#define NOISE_STD 0.015625f     // max(1/64, 1e-6)
#define INV_NOISE_STD 64.0f
#define OUT_GATES (B_ * S_ * E_)   // 2097152
#define APART 32                   // striped global accumulator copies

typedef __attribute__((ext_vector_type(8))) short short8;
typedef __attribute__((ext_vector_type(4))) float f32x4;

// workspace layout (float offsets)
// [0 .. 32768): Wg as bf16 [64][1024] (ushort)
#define WS_GW   32768                    // GW[64]
#define WS_BW   32832                    // BW[64]
#define WS_IMP  32896                    // APART x [8][64]
#define WS_SGN  (WS_IMP + APART * 512)   // APART x [64]
#define WS_CNT  (WS_SGN + APART * 64)    // APART x [64]
#define WS_SP   (WS_CNT + APART * 64)    // APART x [2]
#define WS_NACC (APART * 512 + APART * 64 + APART * 64 + APART * 2)

__device__ __forceinline__ float wave_sum64(float v) {
#pragma unroll
  for (int o = 32; o > 0; o >>= 1) v += __shfl_xor(v, o);
  return v;
}

// ---------------- prep: Wg(bf16) = gamma*W, GW/BW reductions, zero accums ----
__global__ void router_prep(const float* __restrict__ W,
                            const float* __restrict__ gamma,
                            const float* __restrict__ beta,
                            float* __restrict__ ws) {
  if (blockIdx.x >= E_) {
    const int z = blockIdx.x - E_;   // 0..7
    for (int i = z * 256 + threadIdx.x; i < WS_NACC; i += 8 * 256)
      ws[WS_IMP + i] = 0.0f;
    return;
  }
  const int e = blockIdx.x;
  unsigned short* wgb = (unsigned short*)ws;
  float gw = 0.0f, bw = 0.0f;
  for (int d = threadIdx.x; d < D_; d += 256) {
    float wv = W[e * D_ + d];
    float pv = gamma[d] * wv;
    union { __hip_bfloat16 h; unsigned short u; } cv;
    cv.h = __float2bfloat16(pv);
    wgb[e * D_ + d] = cv.u;
    gw += __bfloat162float(cv.h);   // sum of ROUNDED values (consistency)
    bw += beta[d] * wv;
  }
  __shared__ float sred[8];
  gw = wave_sum64(gw);
  bw = wave_sum64(bw);
  const int w = threadIdx.x >> 6, lane = threadIdx.x & 63;
  if (lane == 0) { sred[w] = gw; sred[4 + w] = bw; }
  __syncthreads();
  if (threadIdx.x == 0) {
    ws[WS_GW + e] = sred[0] + sred[1] + sred[2] + sred[3];
    ws[WS_BW + e] = sred[4] + sred[5] + sred[6] + sred[7];
  }
}

// ---------------- main: 4-deep prefetch queue, conflict-free LDS layout -----
// block = 256 thr = 4 waves; block owns 16 rows (r: b=r&7, sl=r>>3, s=2*bid+sl).
// K: 16 steps of 64. X tile in LDS as [ks(2)][row(16)][33] dwords per buffer
// (read banks = lrow+8*kh+j mod 32 -> exact 2-way; write banks 2-way; both free).
// Register queue q[4]: step s issues load for s+4, writes s+1 to LDS at end
// -> 3 steps of latency budget. LN stats: staging threads accumulate own
// values, one 16-lane reduce at step 14. Wave w = experts [16w,16w+16), full K.
__global__ void __launch_bounds__(256, 8)
router_main(const float* __restrict__ X, const float* __restrict__ noise,
            float* __restrict__ out, float* __restrict__ ws) {
  __shared__ __align__(16) float XlF[2 * 1088];  // 2 bufs x [2][16][33]+pad
  __shared__ __align__(16) float Lg[1088];       // [16][68] logits
  __shared__ float svs[16], sv2s[16];
  __shared__ float cntl[64];
  __shared__ float red4[4];
  float* gcl = XlF;          // epilogue aliases (GEMM LDS reads done by then)
  float* gnl = XlF + 1088;
  float* pl  = Lg;           // per-lane read-then-write -> safe alias

  const int t = threadIdx.x;
  const int w = t >> 6, lane = t & 63;
  const int lrow = lane & 15, kh = lane >> 4;
  const int s0 = blockIdx.x * 2;

  // staging: thread t -> row r_t = t>>4, dwords c_t..c_t+3 of each 64-step
  const int r_t = t >> 4, c_t = (t & 15) * 4;
  const int ks_t = c_t >> 5, cw = c_t & 31;
  const int ldso = ks_t * 528 + r_t * 33 + cw;
  const float* __restrict__ xstage =
      X + ((size_t)(r_t & 7) * S_ + (size_t)(s0 + (r_t >> 3))) * D_ + c_t;

  // B: wave w experts [16w,16w+16); lane&15 = expert-in-tile, kh = k-slice
  const unsigned short* __restrict__ bp =
      (const unsigned short*)ws + (16 * w + lrow) * D_ + kh * 8;

  const float gwv = ws[WS_GW + 16 * w + lrow];
  const float bwv = ws[WS_BW + 16 * w + lrow];

  // epilogue indices + EARLY noise load (latency hides under the K-loop)
  const int rr_e = lane >> 4, j_e = lane & 15;
  const int r_e = w * 4 + rr_e;
  const int b_e = r_e & 7, sl_e = r_e >> 3;
  const int s_e = s0 + sl_e;
  const float4 nv =
      *(const float4*)(noise + ((size_t)b_e * S_ + s_e) * E_ + 4 * j_e);

  // prefetch queue: q[i] holds step data; preload steps 0..3
  float4 q[4];
  q[0] = *(const float4*)(xstage);
  q[1] = *(const float4*)(xstage + 64);
  q[2] = *(const float4*)(xstage + 128);
  q[3] = *(const float4*)(xstage + 192);

  float ssv = 0.0f, ssv2 = 0.0f;
  // step 0 -> LDS buf 0 (+stats)
  *(float4*)(&XlF[ldso]) = q[0];
  ssv  += (q[0].x + q[0].y) + (q[0].z + q[0].w);
  ssv2 = fmaf(q[0].x, q[0].x, ssv2); ssv2 = fmaf(q[0].y, q[0].y, ssv2);
  ssv2 = fmaf(q[0].z, q[0].z, ssv2); ssv2 = fmaf(q[0].w, q[0].w, ssv2);

  f32x4 acc = {0.f, 0.f, 0.f, 0.f};

#pragma unroll
  for (int s = 0; s < 16; ++s) {
    __syncthreads();                         // buf[s&1] ready
    if (s + 4 < 16)                          // issue load for step s+4
      q[s & 3] = *(const float4*)(xstage + (s + 4) * 64);

    short8 bv0 = *(const short8*)(bp + s * 64);
    short8 bv1 = *(const short8*)(bp + s * 64 + 32);
    const float* xb = XlF + (s & 1) * 1088;

#pragma unroll
    for (int ks = 0; ks < 2; ++ks) {
      const float* fr = xb + ks * 528 + lrow * 33 + kh * 8;
      float4 a0 = *(const float4*)(fr);
      float4 a1 = *(const float4*)(fr + 4);
      union { short8 s8; __hip_bfloat162 h[4]; } u;
      u.h[0] = __float22bfloat162_rn(make_float2(a0.x, a0.y));
      u.h[1] = __float22bfloat162_rn(make_float2(a0.z, a0.w));
      u.h[2] = __float22bfloat162_rn(make_float2(a1.x, a1.y));
      u.h[3] = __float22bfloat162_rn(make_float2(a1.z, a1.w));
      acc = __builtin_amdgcn_mfma_f32_16x16x32_bf16(u.s8, ks ? bv1 : bv0,
                                                    acc, 0, 0, 0);
    }

    if (s + 1 < 16) {                        // write step s+1 (loaded at s-3)
      float4 wv = q[(s + 1) & 3];
      *(float4*)(&XlF[((s + 1) & 1) * 1088 + ldso]) = wv;
      ssv  += (wv.x + wv.y) + (wv.z + wv.w);
      ssv2 = fmaf(wv.x, wv.x, ssv2); ssv2 = fmaf(wv.y, wv.y, ssv2);
      ssv2 = fmaf(wv.z, wv.z, ssv2); ssv2 = fmaf(wv.w, wv.w, ssv2);
      if (s == 14) {                         // stats complete: 16-lane reduce
        ssv  += __shfl_xor(ssv, 1);  ssv  += __shfl_xor(ssv, 2);
        ssv  += __shfl_xor(ssv, 4);  ssv  += __shfl_xor(ssv, 8);
        ssv2 += __shfl_xor(ssv2, 1); ssv2 += __shfl_xor(ssv2, 2);
        ssv2 += __shfl_xor(ssv2, 4); ssv2 += __shfl_xor(ssv2, 8);
        if ((lane & 15) == 0) { svs[r_t] = ssv; sv2s[r_t] = ssv2; }
      }
    }
  }

  // logits: C/D layout col=lane&15, row=(lane>>4)*4+i  [m89-verified]
#pragma unroll
  for (int i = 0; i < 4; i++) {
    const int rloc = kh * 4 + i;
    const float mui = svs[rloc] * (1.0f / (float)D_);
    const float var = sv2s[rloc] * (1.0f / (float)D_) - mui * mui;
    const float rsi = rsqrtf(var + 1e-5f);
    Lg[rloc * 68 + 16 * w + lrow] = rsi * (acc[i] - mui * gwv) + bwv;
  }
  if (t < 64) cntl[t] = 0.0f;
  __syncthreads();

  // ---- epilogue: all 4 waves; wave w rows 4w..4w+3; lane=(rr,j), 4 experts --
  {
    const int r = r_e, b = b_e, s = s_e, j = j_e;
    float4 lv = *(const float4*)(Lg + r * 68 + 4 * j);
    float ln0 = fmaf(NOISE_STD, nv.x, lv.x);
    float ln1 = fmaf(NOISE_STD, nv.y, lv.y);
    float ln2 = fmaf(NOISE_STD, nv.z, lv.z);
    float ln3 = fmaf(NOISE_STD, nv.w, lv.w);

    // combined max+secondmax of noisy logits (m1 also shifts clean softmax)
    float m1 = ln0, m2 = -INFINITY;
    m2 = fmaxf(m2, fminf(m1, ln1)); m1 = fmaxf(m1, ln1);
    m2 = fmaxf(m2, fminf(m1, ln2)); m1 = fmaxf(m1, ln2);
    m2 = fmaxf(m2, fminf(m1, ln3)); m1 = fmaxf(m1, ln3);
#pragma unroll
    for (int o = 1; o <= 8; o <<= 1) {
      float o1 = __shfl_xor(m1, o), o2 = __shfl_xor(m2, o);
      m2 = fmaxf(fmaxf(m2, o2), fminf(m1, o1));
      m1 = fmaxf(m1, o1);
    }
    float ec0 = __expf(lv.x - m1), ec1 = __expf(lv.y - m1);
    float ec2 = __expf(lv.z - m1), ec3 = __expf(lv.w - m1);
    float en0 = __expf(ln0 - m1), en1 = __expf(ln1 - m1);
    float en2 = __expf(ln2 - m1), en3 = __expf(ln3 - m1);
    float sg = (ec0 + ec1) + (ec2 + ec3);
    float sn = (en0 + en1) + (en2 + en3);
#pragma unroll
    for (int o = 1; o <= 8; o <<= 1) {
      sg += __shfl_xor(sg, o);
      sn += __shfl_xor(sn, o);
    }
    const float rg = 1.0f / sg, rn = 1.0f / sn;
    float4 gnv = { en0 * rn, en1 * rn, en2 * rn, en3 * rn };
    float4 gcv = { ec0 * rg, ec1 * rg, ec2 * rg, ec3 * rg };
    float z0 = fminf(fmaxf((m2 - lv.x) * INV_NOISE_STD, -10.f), 10.f);
    float z1 = fminf(fmaxf((m2 - lv.y) * INV_NOISE_STD, -10.f), 10.f);
    float z2 = fminf(fmaxf((m2 - lv.z) * INV_NOISE_STD, -10.f), 10.f);
    float z3 = fminf(fmaxf((m2 - lv.w) * INV_NOISE_STD, -10.f), 10.f);
    float4 pv = { 0.5f * (1.0f + erff(z0 * 0.70710678118654752f)),
                  0.5f * (1.0f + erff(z1 * 0.70710678118654752f)),
                  0.5f * (1.0f + erff(z2 * 0.70710678118654752f)),
                  0.5f * (1.0f + erff(z3 * 0.70710678118654752f)) };

    *(float4*)(out + ((size_t)b * S_ + s) * E_ + 4 * j) = gnv;
    *(float4*)(gnl + r * 68 + 4 * j) = gnv;
    *(float4*)(gcl + r * 68 + 4 * j) = gcv;
    *(float4*)(pl  + r * 68 + 4 * j) = pv;
    // top-1 count via equality (ties vanishingly rare; softmax is monotone)
    if (ln0 == m1) atomicAdd(&cntl[4 * j + 0], 1.0f);
    if (ln1 == m1) atomicAdd(&cntl[4 * j + 1], 1.0f);
    if (ln2 == m1) atomicAdd(&cntl[4 * j + 2], 1.0f);
    if (ln3 == m1) atomicAdd(&cntl[4 * j + 3], 1.0f);
  }
  __syncthreads();

  // ---- phase 2: block-level reductions -> striped global accumulators ----
  const int pc = blockIdx.x & (APART - 1);
  {
    int b0i = t >> 6, e0i = t & 63;
    float v0 = gcl[b0i * 68 + e0i] + gcl[(8 + b0i) * 68 + e0i];
    atomicAdd(&ws[WS_IMP + pc * 512 + t], v0);
    int p1 = t + 256;
    int b1i = p1 >> 6, e1i = p1 & 63;
    float v1 = gcl[b1i * 68 + e1i] + gcl[(8 + b1i) * 68 + e1i];
    atomicAdd(&ws[WS_IMP + pc * 512 + p1], v1);
  }
  if (t < 64) {
    float sgn = 0.0f;
#pragma unroll
    for (int r = 0; r < 16; r++) sgn += gnl[r * 68 + t];
    atomicAdd(&ws[WS_SGN + pc * 64 + t], sgn);
  } else if (t < 128) {
    atomicAdd(&ws[WS_CNT + pc * 64 + (t - 64)], cntl[t - 64]);
  } else {
    const int idx = t - 128;            // [0,128): sl = idx>>6, e = idx&63
    const int slc = idx >> 6, e = idx & 63;
    float P = 0.0f;
#pragma unroll
    for (int b = 0; b < 8; b++) P += pl[(slc * 8 + b) * 68 + e];
    float c1 = P * 0.125f;
    float c2 = c1 * c1;
    c1 = wave_sum64(c1);
    c2 = wave_sum64(c2);
    if (lane == 0) { red4[(w - 2) * 2] = c1; red4[(w - 2) * 2 + 1] = c2; }
  }
  __syncthreads();
  if (t == 0) {
    atomicAdd(&ws[WS_SP + pc * 2 + 0], red4[0] + red4[2]);
    atomicAdd(&ws[WS_SP + pc * 2 + 1], red4[1] + red4[3]);
  }
}

// ---------------- finalize: reduce APART copies, 3 scalar losses ------------
__global__ void router_final(const float* __restrict__ ws, float* __restrict__ out) {
  const int lane = threadIdx.x;  // 64 threads = 1 wave
  float impsum = 0.0f;
  for (int b = 0; b < B_; ++b) {
    float v = 0.0f;
    for (int c = 0; c < APART; ++c) v += ws[WS_IMP + c * 512 + b * 64 + lane];
    float sfull = wave_sum64(v);
    float mean = sfull * (1.0f / 64.0f);
    float d = v - mean;
    float ss = wave_sum64(d * d);
    impsum += (ss / 63.0f) / (mean * mean);
  }
  float importance = impsum * (1.0f / (float)B_);

  float sp1 = 0.0f, sp2 = 0.0f;
  if (lane < APART) { sp1 = ws[WS_SP + lane * 2]; sp2 = ws[WS_SP + lane * 2 + 1]; }
  sp1 = wave_sum64(sp1);
  sp2 = wave_sum64(sp2);
  const float N = (float)(S_ * E_);
  float meanp = sp1 / N;
  float varp = sp2 / N - meanp * meanp;
  float load = varp / (meanp * meanp);

  float sgn = 0.0f, cnt = 0.0f;
  for (int c = 0; c < APART; ++c) {
    sgn += ws[WS_SGN + c * 64 + lane];
    cnt += ws[WS_CNT + c * 64 + lane];
  }
  const float inv_rows = 1.0f / (float)(B_ * S_);
  float te = (cnt * inv_rows) * (sgn * inv_rows);
  float gs = wave_sum64(te) * (float)E_;

  if (lane == 0) {
    out[OUT_GATES + 0] = importance + load;  // aux (GSHARD_W = 0)
    out[OUT_GATES + 1] = gs;
    out[OUT_GATES + 2] = importance;
    out[OUT_GATES + 3] = load;
  }
}

extern "C" void kernel_launch(void* const* d_in, const int* in_sizes, int n_in,
                              void* d_out, int out_size, void* d_ws, size_t ws_size,
                              hipStream_t stream) {
  (void)in_sizes; (void)n_in; (void)out_size; (void)ws_size;
  const float* X     = (const float*)d_in[0];
  const float* noise = (const float*)d_in[1];
  const float* gamma = (const float*)d_in[2];
  const float* beta  = (const float*)d_in[3];
  const float* W     = (const float*)d_in[4];
  float* out = (float*)d_out;
  float* ws  = (float*)d_ws;

  router_prep<<<dim3(E_ + 8), dim3(256), 0, stream>>>(W, gamma, beta, ws);
  router_main<<<dim3(S_ / 2), dim3(256), 0, stream>>>(X, noise, out, ws);
  router_final<<<dim3(1), dim3(64), 0, stream>>>(ws, out);
}

// Round 7
// 78.077 us; speedup vs baseline: 2.1945x; 1.0642x over previous
//
#include <hip/hip_runtime.h>
#include <hip/hip_bf16.h>
#include <math.h>

// NoisyTopExpertsPerItemRouter: B=8,S=4096,D=1024,E=64,K=2
#define B_ 8
#define S_ 4096
#define D_ 1024
#define E_ 64
#define NOISE_STD 0.015625f     // max(1/64, 1e-6)
#define INV_NOISE_STD 64.0f
#define OUT_GATES (B_ * S_ * E_)   // 2097152
#define APART 32                   // striped global accumulator copies

typedef __attribute__((ext_vector_type(8))) short short8;
typedef __attribute__((ext_vector_type(4))) float f32x4;

// workspace layout (float offsets)
// [0 .. 32768): Wg as bf16 [64][1024] (ushort)
#define WS_GW   32768                    // GW[64]
#define WS_BW   32832                    // BW[64]
#define WS_IMP  32896                    // APART x [8][64]
#define WS_SGN  (WS_IMP + APART * 512)   // APART x [64]
#define WS_CNT  (WS_SGN + APART * 64)    // APART x [64]
#define WS_SP   (WS_CNT + APART * 64)    // APART x [2]
#define WS_NACC (APART * 512 + APART * 64 + APART * 64 + APART * 2)

__device__ __forceinline__ float wave_sum64(float v) {
#pragma unroll
  for (int o = 32; o > 0; o >>= 1) v += __shfl_xor(v, o);
  return v;
}

// ---------------- prep: Wg(bf16) = gamma*W, GW/BW reductions, zero accums ----
__global__ void router_prep(const float* __restrict__ W,
                            const float* __restrict__ gamma,
                            const float* __restrict__ beta,
                            float* __restrict__ ws) {
  if (blockIdx.x >= E_) {
    const int z = blockIdx.x - E_;   // 0..7
    for (int i = z * 256 + threadIdx.x; i < WS_NACC; i += 8 * 256)
      ws[WS_IMP + i] = 0.0f;
    return;
  }
  const int e = blockIdx.x;
  unsigned short* wgb = (unsigned short*)ws;
  float gw = 0.0f, bw = 0.0f;
  for (int d = threadIdx.x; d < D_; d += 256) {
    float wv = W[e * D_ + d];
    float pv = gamma[d] * wv;
    union { __hip_bfloat16 h; unsigned short u; } cv;
    cv.h = __float2bfloat16(pv);
    wgb[e * D_ + d] = cv.u;
    gw += __bfloat162float(cv.h);   // sum of ROUNDED values (consistency)
    bw += beta[d] * wv;
  }
  __shared__ float sred[8];
  gw = wave_sum64(gw);
  bw = wave_sum64(bw);
  const int w = threadIdx.x >> 6, lane = threadIdx.x & 63;
  if (lane == 0) { sred[w] = gw; sred[4 + w] = bw; }
  __syncthreads();
  if (threadIdx.x == 0) {
    ws[WS_GW + e] = sred[0] + sred[1] + sred[2] + sred[3];
    ws[WS_BW + e] = sred[4] + sred[5] + sred[6] + sred[7];
  }
}

// ---------------- main: K-split-4, queued X AND B, counted vmcnt ------------
// block = 256 thr = 4 waves; block owns 16 rows (r: b=r&7, sl=r>>3, s=2*bid+sl).
// Wave w = K-chunk [256w,256w+256) for ALL 16 rows x 64 experts (4 MFMA chains).
// Register queues: qx[4] (X, issue j+4), qb[2] (B, issue j+2). Every consumer
// waits on a COUNTED vmcnt (data >=2 iters old) -- never vmcnt(0): the FIFO
// drain that capped R3-R6 at ~85us is gone. No barriers in the loop.
__global__ void __launch_bounds__(256, 4)
router_main(const float* __restrict__ X, const float* __restrict__ noise,
            float* __restrict__ out, float* __restrict__ ws) {
  __shared__ __align__(16) float Pbuf[3072];   // acc exchange; then gcl/gnl
  __shared__ __align__(16) float Lg[1088];     // [16][68] logits
  __shared__ float svp[4][16], sv2p[4][16];
  __shared__ float cntl[64];
  __shared__ float red4[4];
  f32x4* Pp  = (f32x4*)Pbuf;   // [4 chains][3 srcs][64 lanes] = 12288B
  float* gcl = Pbuf;           // epilogue aliases (exchange reads done)
  float* gnl = Pbuf + 1088;
  float* pl  = Lg;             // per-lane read-then-write -> safe alias

  const int t = threadIdx.x;
  const int w = t >> 6, lane = t & 63;
  const int lrow = lane & 15, kh = lane >> 4;
  const int s0 = blockIdx.x * 2;

  // A-row this lane loads; wave's K-chunk
  const int b_mf = lrow & 7, sl_mf = lrow >> 3;
  const int wko = w * 256 + kh * 8;
  const float* __restrict__ xp =
      X + ((size_t)b_mf * S_ + (size_t)(s0 + sl_mf)) * D_ + wko;
  const unsigned short* __restrict__ wgb = (const unsigned short*)ws;
  const unsigned short* __restrict__ bp0 = wgb + (0  + lrow) * D_ + wko;
  const unsigned short* __restrict__ bp1 = wgb + (16 + lrow) * D_ + wko;
  const unsigned short* __restrict__ bp2 = wgb + (32 + lrow) * D_ + wko;
  const unsigned short* __restrict__ bp3 = wgb + (48 + lrow) * D_ + wko;

  const float gwv = ws[WS_GW + 16 * w + lrow];
  const float bwv = ws[WS_BW + 16 * w + lrow];

  // epilogue indices + EARLY noise load (oldest in queue; lands during GEMM)
  const int rr_e = lane >> 4, j_e = lane & 15;
  const int r_e = w * 4 + rr_e;
  const int b_e = r_e & 7, sl_e = r_e >> 3;
  const int s_e = s0 + sl_e;
  const float4 nv =
      *(const float4*)(noise + ((size_t)b_e * S_ + s_e) * E_ + 4 * j_e);

  // prologue: fill queues (X iters 0..3, B iters 0..1)
  float4 qx[4][2];
  short8 qb[2][4];
#pragma unroll
  for (int j = 0; j < 4; j++) {
    qx[j][0] = *(const float4*)(xp + j * 32);
    qx[j][1] = *(const float4*)(xp + j * 32 + 4);
  }
#pragma unroll
  for (int j = 0; j < 2; j++) {
    qb[j][0] = *(const short8*)(bp0 + j * 32);
    qb[j][1] = *(const short8*)(bp1 + j * 32);
    qb[j][2] = *(const short8*)(bp2 + j * 32);
    qb[j][3] = *(const short8*)(bp3 + j * 32);
  }

  float sv = 0.0f, sv2 = 0.0f;
  f32x4 acc0 = {0.f, 0.f, 0.f, 0.f};
  f32x4 acc1 = {0.f, 0.f, 0.f, 0.f};
  f32x4 acc2 = {0.f, 0.f, 0.f, 0.f};
  f32x4 acc3 = {0.f, 0.f, 0.f, 0.f};

#pragma unroll
  for (int j = 0; j < 8; ++j) {
    if (j + 4 < 8) {                       // issue X for iter j+4 (ring, no WAR)
      qx[(j + 4) & 3][0] = *(const float4*)(xp + (j + 4) * 32);
      qx[(j + 4) & 3][1] = *(const float4*)(xp + (j + 4) * 32 + 4);
    }
    float4 a0 = qx[j & 3][0];
    float4 a1 = qx[j & 3][1];

    union { short8 s8; __hip_bfloat162 h[4]; } u;
    u.h[0] = __float22bfloat162_rn(make_float2(a0.x, a0.y));
    u.h[1] = __float22bfloat162_rn(make_float2(a0.z, a0.w));
    u.h[2] = __float22bfloat162_rn(make_float2(a1.x, a1.y));
    u.h[3] = __float22bfloat162_rn(make_float2(a1.z, a1.w));

    acc0 = __builtin_amdgcn_mfma_f32_16x16x32_bf16(u.s8, qb[j & 1][0], acc0, 0, 0, 0);
    acc1 = __builtin_amdgcn_mfma_f32_16x16x32_bf16(u.s8, qb[j & 1][1], acc1, 0, 0, 0);
    acc2 = __builtin_amdgcn_mfma_f32_16x16x32_bf16(u.s8, qb[j & 1][2], acc2, 0, 0, 0);
    acc3 = __builtin_amdgcn_mfma_f32_16x16x32_bf16(u.s8, qb[j & 1][3], acc3, 0, 0, 0);

    if (j + 2 < 8) {                       // refill B slot just consumed
      qb[j & 1][0] = *(const short8*)(bp0 + (j + 2) * 32);
      qb[j & 1][1] = *(const short8*)(bp1 + (j + 2) * 32);
      qb[j & 1][2] = *(const short8*)(bp2 + (j + 2) * 32);
      qb[j & 1][3] = *(const short8*)(bp3 + (j + 2) * 32);
    }

    sv += (a0.x + a0.y) + (a0.z + a0.w) + (a1.x + a1.y) + (a1.z + a1.w);
    sv2 = fmaf(a0.x, a0.x, sv2); sv2 = fmaf(a0.y, a0.y, sv2);
    sv2 = fmaf(a0.z, a0.z, sv2); sv2 = fmaf(a0.w, a0.w, sv2);
    sv2 = fmaf(a1.x, a1.x, sv2); sv2 = fmaf(a1.y, a1.y, sv2);
    sv2 = fmaf(a1.z, a1.z, sv2); sv2 = fmaf(a1.w, a1.w, sv2);
  }

  // per-row LN stats partial (this wave's 256 k's): combine 4 kh lanes
  sv  += __shfl_xor(sv, 16);  sv  += __shfl_xor(sv, 32);
  sv2 += __shfl_xor(sv2, 16); sv2 += __shfl_xor(sv2, 32);
  if (lane < 16) { svp[w][lane] = sv; sv2p[w][lane] = sv2; }

  // publish partials for the 3 chains we don't own (chain c combined by wave c)
  if (w != 0) Pp[(0 * 3 + (w - 1)) * 64 + lane] = acc0;
  if (w != 1) Pp[(1 * 3 + (w - (w > 1))) * 64 + lane] = acc1;
  if (w != 2) Pp[(2 * 3 + (w - (w > 2))) * 64 + lane] = acc2;
  if (w != 3) Pp[(3 * 3 + w) * 64 + lane] = acc3;
  __syncthreads();

  // wave w combines chain w: own acc_w (K-chunk w) + 3 published partials
  f32x4 mine = (w == 0) ? acc0 : (w == 1) ? acc1 : (w == 2) ? acc2 : acc3;
  f32x4 asum = mine + Pp[(w * 3 + 0) * 64 + lane] +
               Pp[(w * 3 + 1) * 64 + lane] + Pp[(w * 3 + 2) * 64 + lane];

  const float svr  = (svp[0][lrow] + svp[1][lrow]) + (svp[2][lrow] + svp[3][lrow]);
  const float sv2r = (sv2p[0][lrow] + sv2p[1][lrow]) + (sv2p[2][lrow] + sv2p[3][lrow]);
  float mu = svr * (1.0f / (float)D_);
  float var = sv2r * (1.0f / (float)D_) - mu * mu;
  float rs = rsqrtf(var + 1e-5f);

  // C/D layout: col(expert-in-tile)=lane&15, row=(lane>>4)*4+i  [m89-verified]
#pragma unroll
  for (int i = 0; i < 4; i++) {
    const int rloc = kh * 4 + i;
    const float mui = __shfl(mu, kh * 4 + i);   // lane (kh*4+i) holds row kh*4+i
    const float rsi = __shfl(rs, kh * 4 + i);
    Lg[rloc * 68 + 16 * w + lrow] = rsi * (asum[i] - mui * gwv) + bwv;
  }
  if (t < 64) cntl[t] = 0.0f;
  __syncthreads();   // logits ready; Pp reads done -> gcl/gnl reusable

  // ---- epilogue: all 4 waves; wave w rows 4w..4w+3; lane=(rr,j), 4 experts --
  {
    const int r = r_e, b = b_e, s = s_e, j = j_e;
    float4 lv = *(const float4*)(Lg + r * 68 + 4 * j);
    float ln0 = fmaf(NOISE_STD, nv.x, lv.x);
    float ln1 = fmaf(NOISE_STD, nv.y, lv.y);
    float ln2 = fmaf(NOISE_STD, nv.z, lv.z);
    float ln3 = fmaf(NOISE_STD, nv.w, lv.w);

    // combined max+secondmax of noisy logits (m1 also shifts clean softmax)
    float m1 = ln0, m2 = -INFINITY;
    m2 = fmaxf(m2, fminf(m1, ln1)); m1 = fmaxf(m1, ln1);
    m2 = fmaxf(m2, fminf(m1, ln2)); m1 = fmaxf(m1, ln2);
    m2 = fmaxf(m2, fminf(m1, ln3)); m1 = fmaxf(m1, ln3);
#pragma unroll
    for (int o = 1; o <= 8; o <<= 1) {
      float o1 = __shfl_xor(m1, o), o2 = __shfl_xor(m2, o);
      m2 = fmaxf(fmaxf(m2, o2), fminf(m1, o1));
      m1 = fmaxf(m1, o1);
    }
    float ec0 = __expf(lv.x - m1), ec1 = __expf(lv.y - m1);
    float ec2 = __expf(lv.z - m1), ec3 = __expf(lv.w - m1);
    float en0 = __expf(ln0 - m1), en1 = __expf(ln1 - m1);
    float en2 = __expf(ln2 - m1), en3 = __expf(ln3 - m1);
    float sg = (ec0 + ec1) + (ec2 + ec3);
    float sn = (en0 + en1) + (en2 + en3);
#pragma unroll
    for (int o = 1; o <= 8; o <<= 1) {
      sg += __shfl_xor(sg, o);
      sn += __shfl_xor(sn, o);
    }
    const float rg = 1.0f / sg, rn = 1.0f / sn;
    float4 gnv = { en0 * rn, en1 * rn, en2 * rn, en3 * rn };
    float4 gcv = { ec0 * rg, ec1 * rg, ec2 * rg, ec3 * rg };
    float z0 = fminf(fmaxf((m2 - lv.x) * INV_NOISE_STD, -10.f), 10.f);
    float z1 = fminf(fmaxf((m2 - lv.y) * INV_NOISE_STD, -10.f), 10.f);
    float z2 = fminf(fmaxf((m2 - lv.z) * INV_NOISE_STD, -10.f), 10.f);
    float z3 = fminf(fmaxf((m2 - lv.w) * INV_NOISE_STD, -10.f), 10.f);
    float4 pv = { 0.5f * (1.0f + erff(z0 * 0.70710678118654752f)),
                  0.5f * (1.0f + erff(z1 * 0.70710678118654752f)),
                  0.5f * (1.0f + erff(z2 * 0.70710678118654752f)),
                  0.5f * (1.0f + erff(z3 * 0.70710678118654752f)) };

    *(float4*)(out + ((size_t)b * S_ + s) * E_ + 4 * j) = gnv;
    *(float4*)(gnl + r * 68 + 4 * j) = gnv;
    *(float4*)(gcl + r * 68 + 4 * j) = gcv;
    *(float4*)(pl  + r * 68 + 4 * j) = pv;
    // top-1 count via equality (ties vanishingly rare; softmax is monotone)
    if (ln0 == m1) atomicAdd(&cntl[4 * j + 0], 1.0f);
    if (ln1 == m1) atomicAdd(&cntl[4 * j + 1], 1.0f);
    if (ln2 == m1) atomicAdd(&cntl[4 * j + 2], 1.0f);
    if (ln3 == m1) atomicAdd(&cntl[4 * j + 3], 1.0f);
  }
  __syncthreads();

  // ---- phase 2: block-level reductions -> striped global accumulators ----
  const int pc = blockIdx.x & (APART - 1);
  {
    int b0i = t >> 6, e0i = t & 63;
    float v0 = gcl[b0i * 68 + e0i] + gcl[(8 + b0i) * 68 + e0i];
    atomicAdd(&ws[WS_IMP + pc * 512 + t], v0);
    int p1 = t + 256;
    int b1i = p1 >> 6, e1i = p1 & 63;
    float v1 = gcl[b1i * 68 + e1i] + gcl[(8 + b1i) * 68 + e1i];
    atomicAdd(&ws[WS_IMP + pc * 512 + p1], v1);
  }
  if (t < 64) {
    float sgn = 0.0f;
#pragma unroll
    for (int r = 0; r < 16; r++) sgn += gnl[r * 68 + t];
    atomicAdd(&ws[WS_SGN + pc * 64 + t], sgn);
  } else if (t < 128) {
    atomicAdd(&ws[WS_CNT + pc * 64 + (t - 64)], cntl[t - 64]);
  } else {
    const int idx = t - 128;            // [0,128): sl = idx>>6, e = idx&63
    const int slc = idx >> 6, e = idx & 63;
    float P = 0.0f;
#pragma unroll
    for (int b = 0; b < 8; b++) P += pl[(slc * 8 + b) * 68 + e];
    float c1 = P * 0.125f;
    float c2 = c1 * c1;
    c1 = wave_sum64(c1);
    c2 = wave_sum64(c2);
    if (lane == 0) { red4[(w - 2) * 2] = c1; red4[(w - 2) * 2 + 1] = c2; }
  }
  __syncthreads();
  if (t == 0) {
    atomicAdd(&ws[WS_SP + pc * 2 + 0], red4[0] + red4[2]);
    atomicAdd(&ws[WS_SP + pc * 2 + 1], red4[1] + red4[3]);
  }
}

// ---------------- finalize: reduce APART copies, 3 scalar losses ------------
__global__ void router_final(const float* __restrict__ ws, float* __restrict__ out) {
  const int lane = threadIdx.x;  // 64 threads = 1 wave
  float impsum = 0.0f;
  for (int b = 0; b < B_; ++b) {
    float v = 0.0f;
    for (int c = 0; c < APART; ++c) v += ws[WS_IMP + c * 512 + b * 64 + lane];
    float sfull = wave_sum64(v);
    float mean = sfull * (1.0f / 64.0f);
    float d = v - mean;
    float ss = wave_sum64(d * d);
    impsum += (ss / 63.0f) / (mean * mean);
  }
  float importance = impsum * (1.0f / (float)B_);

  float sp1 = 0.0f, sp2 = 0.0f;
  if (lane < APART) { sp1 = ws[WS_SP + lane * 2]; sp2 = ws[WS_SP + lane * 2 + 1]; }
  sp1 = wave_sum64(sp1);
  sp2 = wave_sum64(sp2);
  const float N = (float)(S_ * E_);
  float meanp = sp1 / N;
  float varp = sp2 / N - meanp * meanp;
  float load = varp / (meanp * meanp);

  float sgn = 0.0f, cnt = 0.0f;
  for (int c = 0; c < APART; ++c) {
    sgn += ws[WS_SGN + c * 64 + lane];
    cnt += ws[WS_CNT + c * 64 + lane];
  }
  const float inv_rows = 1.0f / (float)(B_ * S_);
  float te = (cnt * inv_rows) * (sgn * inv_rows);
  float gs = wave_sum64(te) * (float)E_;

  if (lane == 0) {
    out[OUT_GATES + 0] = importance + load;  // aux (GSHARD_W = 0)
    out[OUT_GATES + 1] = gs;
    out[OUT_GATES + 2] = importance;
    out[OUT_GATES + 3] = load;
  }
}

extern "C" void kernel_launch(void* const* d_in, const int* in_sizes, int n_in,
                              void* d_out, int out_size, void* d_ws, size_t ws_size,
                              hipStream_t stream) {
  (void)in_sizes; (void)n_in; (void)out_size; (void)ws_size;
  const float* X     = (const float*)d_in[0];
  const float* noise = (const float*)d_in[1];
  const float* gamma = (const float*)d_in[2];
  const float* beta  = (const float*)d_in[3];
  const float* W     = (const float*)d_in[4];
  float* out = (float*)d_out;
  float* ws  = (float*)d_ws;

  router_prep<<<dim3(E_ + 8), dim3(256), 0, stream>>>(W, gamma, beta, ws);
  router_main<<<dim3(S_ / 2), dim3(256), 0, stream>>>(X, noise, out, ws);
  router_final<<<dim3(1), dim3(64), 0, stream>>>(ws, out);
}